// Round 1
// baseline (1539.502 us; speedup 1.0000x reference)
//
#include <hip/hip_runtime.h>
#include <hip/hip_bf16.h>

#define B_  4
#define T_  2048
#define DM  1024
#define H_  4
#define DK_ 128
#define DV_ 256
#define KD  512     // H_*DK_
#define VD  1024    // H_*DV_
#define NCH 32      // num chunks
#define CC  64      // chunk len
#define BT  8192    // B_*T_
#define SCALE 0.08838834764831845f   // 1/sqrt(128)
#define GNORM_INV 0.0625f            // 1/16

// ---------------------------------------------------------------------------
// Generic f32 GEMM: C[M,N] = A[M,K] @ W[K,N], 64x64 tile, 256 thr, 4x4 micro
// ---------------------------------------------------------------------------
__global__ __launch_bounds__(256)
void gemm_f32(const float* __restrict__ A, const float* __restrict__ W,
              float* __restrict__ C, int M, int K, int N) {
    __shared__ float as[16][68];   // [k][row] (A transposed)
    __shared__ float bs[16][68];   // [k][col]
    const int t = threadIdx.x;
    const int row0 = blockIdx.x * 64, col0 = blockIdx.y * 64;
    const int ty = t >> 4, tx = t & 15;
    const int li = t >> 2, ls = (t & 3) * 4;    // A: row li, k-seg ls
    const int lk = t >> 4, lc = (t & 15) * 4;   // W: k lk, col-seg lc

    const float* Ap = A + (size_t)(row0 + li) * K + ls;
    const float* Wp = W + (size_t)lk * N + col0 + lc;

    float acc[4][4];
    #pragma unroll
    for (int r = 0; r < 4; ++r)
        #pragma unroll
        for (int c = 0; c < 4; ++c) acc[r][c] = 0.f;

    for (int k0 = 0; k0 < K; k0 += 16) {
        float4 av = *(const float4*)(Ap + k0);
        float4 bv = *(const float4*)(Wp + (size_t)k0 * N);
        __syncthreads();
        as[ls+0][li] = av.x; as[ls+1][li] = av.y;
        as[ls+2][li] = av.z; as[ls+3][li] = av.w;
        *(float4*)&bs[lk][lc] = bv;
        __syncthreads();
        #pragma unroll
        for (int kk = 0; kk < 16; ++kk) {
            float4 a4 = *(const float4*)&as[kk][ty*4];
            float4 b4 = *(const float4*)&bs[kk][tx*4];
            float ar[4] = {a4.x, a4.y, a4.z, a4.w};
            float br[4] = {b4.x, b4.y, b4.z, b4.w};
            #pragma unroll
            for (int r = 0; r < 4; ++r)
                #pragma unroll
                for (int c = 0; c < 4; ++c)
                    acc[r][c] += ar[r] * br[c];
        }
    }
    #pragma unroll
    for (int r = 0; r < 4; ++r) {
        float4 ov = make_float4(acc[r][0], acc[r][1], acc[r][2], acc[r][3]);
        *(float4*)&C[(size_t)(row0 + ty*4 + r) * N + col0 + tx*4] = ov;
    }
}

// ---------------------------------------------------------------------------
// Low-rank gate stage 1: tmp[BT,16] = x @ Wgk1
// ---------------------------------------------------------------------------
__global__ __launch_bounds__(256)
void lowrank_kernel(const float* __restrict__ x, const float* __restrict__ W1,
                    float* __restrict__ tmp) {
    const int t = threadIdx.x;
    const int r = t >> 4, c = t & 15;
    const int row = blockIdx.x * 16 + r;
    const float* xp = x + (size_t)row * DM;
    float acc = 0.f;
    for (int kk = 0; kk < DM; kk += 4) {
        float4 xv = *(const float4*)(xp + kk);
        acc += xv.x * W1[(kk+0)*16 + c];
        acc += xv.y * W1[(kk+1)*16 + c];
        acc += xv.z * W1[(kk+2)*16 + c];
        acc += xv.w * W1[(kk+3)*16 + c];
    }
    tmp[row*16 + c] = acc;
}

// ---------------------------------------------------------------------------
// Gate stage 2: gk[BT,512] = log_sigmoid(tmp @ Wgk2 + b) / 16
// ---------------------------------------------------------------------------
__global__ __launch_bounds__(256)
void gatek_kernel(const float* __restrict__ tmp, const float* __restrict__ W2,
                  const float* __restrict__ bias, float* __restrict__ gk) {
    const int idx = blockIdx.x * 256 + threadIdx.x;   // over BT*KD
    const int bt = idx >> 9, c = idx & 511;
    float z = bias[c];
    #pragma unroll
    for (int j = 0; j < 16; ++j)
        z += tmp[bt*16 + j] * W2[j*KD + c];
    float ls = fminf(z, 0.f) - log1pf(expf(-fabsf(z)));
    gk[idx] = ls * GNORM_INV;
}

// ---------------------------------------------------------------------------
// Gate prep (in place): q->qg, k->k_intra, gk->kg; writes glast.
// block = (b,nc,h), 128 threads (one per dk channel)
// ---------------------------------------------------------------------------
__global__ __launch_bounds__(128)
void gateprep_kernel(float* __restrict__ q, float* __restrict__ k,
                     float* __restrict__ gk, float* __restrict__ glast) {
    const int bid = blockIdx.x;
    const int h  = bid % H_;
    const int bn = bid / H_;
    const int nc = bn % NCH, b = bn / NCH;
    const int d = threadIdx.x;
    const int t0 = b*T_ + nc*CC;
    const int base = t0*KD + h*DK_ + d;

    float total = 0.f;
    for (int i = 0; i < CC; ++i) total += gk[base + i*KD];

    float G = 0.f;
    for (int i = 0; i < CC; ++i) {
        const int idx = base + i*KD;
        float gv = gk[idx];
        G += gv;
        float qv = q[idx], kv = k[idx];
        q[idx]  = qv * expf(G) * SCALE;      // qg
        k[idx]  = kv * expf(-G);             // k_intra
        gk[idx] = kv * expf(total - G);      // kg
    }
    glast[((b*H_ + h)*NCH + nc)*DK_ + d] = expf(total);
}

// ---------------------------------------------------------------------------
// Intra-chunk: A = tril(qg @ k_intra^T); o = A @ v.  block=(b,nc,h), 256 thr
// ---------------------------------------------------------------------------
__global__ __launch_bounds__(256)
void intra_kernel(const float* __restrict__ qg, const float* __restrict__ ki,
                  const float* __restrict__ v, float* __restrict__ o) {
    // LDS: qsT[128][68] + kiT[128][68] (region0), As[64][68]; vs[64][260] overlays region0
    __shared__ __align__(16) char smem_raw[34816*2 + 17408];
    float (*qsT)[68] = (float(*)[68])(smem_raw);
    float (*kiT)[68] = (float(*)[68])(smem_raw + 34816);
    float (*As)[68]  = (float(*)[68])(smem_raw + 69632);
    float (*vs)[260] = (float(*)[260])(smem_raw);

    const int bid = blockIdx.x;
    const int h  = bid % H_;
    const int bn = bid / H_;
    const int nc = bn % NCH, b = bn / NCH;
    const int t0 = b*T_ + nc*CC;
    const int t = threadIdx.x;

    // phase 1: load qg, ki (64x128 each), transposed into LDS
    #pragma unroll
    for (int m = 0; m < 8; ++m) {
        const int p = t + m*256;          // float4 id, 2048 total
        const int i = p >> 5;             // row
        const int d4 = (p & 31) * 4;
        const int gidx = (t0+i)*KD + h*DK_ + d4;
        float4 a = *(const float4*)&qg[gidx];
        qsT[d4+0][i] = a.x; qsT[d4+1][i] = a.y; qsT[d4+2][i] = a.z; qsT[d4+3][i] = a.w;
        float4 c = *(const float4*)&ki[gidx];
        kiT[d4+0][i] = c.x; kiT[d4+1][i] = c.y; kiT[d4+2][i] = c.z; kiT[d4+3][i] = c.w;
    }
    __syncthreads();

    // phase 2: A[i][j] = sum_d qg[i][d]*ki[j][d], tril mask, into As
    {
        const int tj = t & 15, ti = t >> 4;
        const int i0 = ti*4, j0 = tj*4;
        float a4[4][4];
        #pragma unroll
        for (int r = 0; r < 4; ++r)
            #pragma unroll
            for (int c = 0; c < 4; ++c) a4[r][c] = 0.f;
        for (int d = 0; d < 128; ++d) {
            float4 qv = *(const float4*)&qsT[d][i0];
            float4 kv = *(const float4*)&kiT[d][j0];
            float qr[4] = {qv.x, qv.y, qv.z, qv.w};
            float kr[4] = {kv.x, kv.y, kv.z, kv.w};
            #pragma unroll
            for (int r = 0; r < 4; ++r)
                #pragma unroll
                for (int c = 0; c < 4; ++c)
                    a4[r][c] += qr[r] * kr[c];
        }
        __syncthreads();   // done reading qsT/kiT before overlay (and before As write races? no: As distinct region; sync needed before vs overlay below)
        #pragma unroll
        for (int r = 0; r < 4; ++r)
            #pragma unroll
            for (int c = 0; c < 4; ++c)
                As[i0+r][j0+c] = (j0+c <= i0+r) ? a4[r][c] : 0.f;
    }
    __syncthreads();

    // phase 3: load v chunk (64x256) into vs (overlays qsT/kiT)
    #pragma unroll
    for (int m = 0; m < 16; ++m) {
        const int p = t + m*256;          // 4096 float4
        const int i = p >> 6;
        const int dv4 = (p & 63) * 4;
        *(float4*)&vs[i][dv4] = *(const float4*)&v[(t0+i)*VD + h*DV_ + dv4];
    }
    __syncthreads();

    // phase 4: o[i][dv] = sum_{j<=i} A[i][j] * v[j][dv]
    {
        const int dv4 = (t & 63) * 4;
        const int ig = t >> 6;            // 4 groups of 16 rows
        for (int r = 0; r < 16; ++r) {
            const int i = ig*16 + r;
            float4 acc = make_float4(0.f, 0.f, 0.f, 0.f);
            for (int j = 0; j <= i; ++j) {
                float Av = As[i][j];
                float4 vv = *(const float4*)&vs[j][dv4];
                acc.x += Av*vv.x; acc.y += Av*vv.y; acc.z += Av*vv.z; acc.w += Av*vv.w;
            }
            *(float4*)&o[(t0+i)*VD + h*DV_ + dv4] = acc;
        }
    }
}

// ---------------------------------------------------------------------------
// Sequential inter-chunk scan. block = (b,h,dv-tile of 64), 256 thr.
// S[128][64] in LDS. o += qg @ S ; S = diag(gl) S + kg^T v
// ---------------------------------------------------------------------------
__global__ __launch_bounds__(256)
void scan_kernel(const float* __restrict__ qg, const float* __restrict__ kg,
                 const float* __restrict__ v, const float* __restrict__ glast,
                 float* __restrict__ o) {
    __shared__ float S[128][68];
    __shared__ float qsc[64][132];
    __shared__ float kgc[64][132];
    __shared__ float vsc[64][68];

    const int bid = blockIdx.x;
    const int dvt = bid & 3, bh = bid >> 2;
    const int h = bh % H_, b = bh / H_;
    const int dv0 = dvt * 64;
    const int t = threadIdx.x;
    const int lv4 = (t & 15) * 4;   // local dv word
    const int grp = t >> 4;         // 0..15

    for (int m = t; m < 128*68; m += 256) ((float*)S)[m] = 0.f;
    __syncthreads();

    for (int nc = 0; nc < NCH; ++nc) {
        const int t0 = b*T_ + nc*CC;
        // stage qg, kg (64x128), v (64x64)
        #pragma unroll
        for (int m = 0; m < 8; ++m) {
            const int p = t + m*256; const int i = p >> 5; const int d4 = (p & 31)*4;
            const int gidx = (t0+i)*KD + h*DK_ + d4;
            *(float4*)&qsc[i][d4] = *(const float4*)&qg[gidx];
            *(float4*)&kgc[i][d4] = *(const float4*)&kg[gidx];
        }
        #pragma unroll
        for (int m = 0; m < 4; ++m) {
            const int p = t + m*256; const int i = p >> 4; const int w4 = (p & 15)*4;
            *(float4*)&vsc[i][w4] = *(const float4*)&v[(t0+i)*VD + h*DV_ + dv0 + w4];
        }
        __syncthreads();

        // o_inter: each thread 4 rows x 4 dv
        #pragma unroll
        for (int r = 0; r < 4; ++r) {
            const int i = grp*4 + r;
            const int obase = (t0+i)*VD + h*DV_ + dv0 + lv4;
            float4 acc = *(float4*)&o[obase];
            for (int d = 0; d < 128; ++d) {
                float qv = qsc[i][d];
                float4 s4 = *(const float4*)&S[d][lv4];
                acc.x += qv*s4.x; acc.y += qv*s4.y; acc.z += qv*s4.z; acc.w += qv*s4.w;
            }
            *(float4*)&o[obase] = acc;
        }
        __syncthreads();

        // state update: each thread owns 8 d x 4 dv of S
        {
            float4 sacc[8];
            const int glb = ((b*H_ + h)*NCH + nc)*DK_;
            #pragma unroll
            for (int dd = 0; dd < 8; ++dd) {
                const int d = grp*8 + dd;
                float gl = glast[glb + d];
                float4 s4 = *(const float4*)&S[d][lv4];
                sacc[dd] = make_float4(s4.x*gl, s4.y*gl, s4.z*gl, s4.w*gl);
            }
            for (int i0 = 0; i0 < 64; i0 += 8) {
                float4 vv[8];
                #pragma unroll
                for (int ii = 0; ii < 8; ++ii)
                    vv[ii] = *(const float4*)&vsc[i0+ii][lv4];
                #pragma unroll
                for (int dd = 0; dd < 8; ++dd) {
                    const int d = grp*8 + dd;
                    #pragma unroll
                    for (int ii = 0; ii < 8; ++ii) {
                        float kv = kgc[i0+ii][d];
                        sacc[dd].x += kv*vv[ii].x; sacc[dd].y += kv*vv[ii].y;
                        sacc[dd].z += kv*vv[ii].z; sacc[dd].w += kv*vv[ii].w;
                    }
                }
            }
            #pragma unroll
            for (int dd = 0; dd < 8; ++dd)
                *(float4*)&S[grp*8+dd][lv4] = sacc[dd];
        }
        __syncthreads();
    }
}

// ---------------------------------------------------------------------------
// Fused RMSNorm(o)*gnw*swish(g), in place on o. One wave per (bt,h) row.
// ---------------------------------------------------------------------------
__global__ __launch_bounds__(256)
void normgate_kernel(float* __restrict__ o, const float* __restrict__ g,
                     const float* __restrict__ gnw) {
    const int t = threadIdx.x;
    const int w = t >> 6, lane = t & 63;
    const int row = blockIdx.x*4 + w;     // over BT*H_
    const int bt = row >> 2, h = row & 3;
    const int base = bt*VD + h*DV_ + lane*4;

    float4 ov = *(float4*)&o[base];
    float ssq = ov.x*ov.x + ov.y*ov.y + ov.z*ov.z + ov.w*ov.w;
    #pragma unroll
    for (int off = 32; off > 0; off >>= 1) ssq += __shfl_xor(ssq, off);
    const float rms = rsqrtf(ssq * (1.0f/DV_) + 1e-5f);

    float4 gv = *(const float4*)&g[base];
    float4 wv = *(const float4*)&gnw[lane*4];
    float4 out;
    out.x = ov.x * rms * wv.x * (gv.x / (1.f + expf(-gv.x)));
    out.y = ov.y * rms * wv.y * (gv.y / (1.f + expf(-gv.y)));
    out.z = ov.z * rms * wv.z * (gv.z / (1.f + expf(-gv.z)));
    out.w = ov.w * rms * wv.w * (gv.w / (1.f + expf(-gv.w)));
    *(float4*)&o[base] = out;
}

// ---------------------------------------------------------------------------
extern "C" void kernel_launch(void* const* d_in, const int* in_sizes, int n_in,
                              void* d_out, int out_size, void* d_ws, size_t ws_size,
                              hipStream_t stream) {
    const float* x    = (const float*)d_in[0];
    const float* Wq   = (const float*)d_in[1];
    const float* Wk   = (const float*)d_in[2];
    const float* Wv   = (const float*)d_in[3];
    const float* Wg   = (const float*)d_in[4];
    const float* Wgk1 = (const float*)d_in[5];
    const float* Wgk2 = (const float*)d_in[6];
    const float* bgk2 = (const float*)d_in[7];
    const float* Wo   = (const float*)d_in[8];
    const float* gnw  = (const float*)d_in[9];

    float* ws    = (float*)d_ws;
    float* q     = ws;                        // BT*KD  (becomes qg)
    float* k     = ws +  4194304;             // BT*KD  (becomes k_intra)
    float* gk    = ws +  8388608;             // BT*KD  (becomes kg)
    float* v     = ws + 12582912;             // BT*VD
    float* g     = ws + 20971520;             // BT*VD
    float* o     = ws + 29360128;             // BT*VD
    float* tmp16 = ws + 37748736;             // BT*16
    float* glast = tmp16 + (size_t)BT*16;     // B*H*NCH*DK

    // projections
    gemm_f32<<<dim3(BT/64,  KD/64), 256, 0, stream>>>(x, Wq, q, BT, DM, KD);
    gemm_f32<<<dim3(BT/64,  KD/64), 256, 0, stream>>>(x, Wk, k, BT, DM, KD);
    gemm_f32<<<dim3(BT/64,  VD/64), 256, 0, stream>>>(x, Wv, v, BT, DM, VD);
    gemm_f32<<<dim3(BT/64,  VD/64), 256, 0, stream>>>(x, Wg, g, BT, DM, VD);

    // gate path
    lowrank_kernel<<<BT/16, 256, 0, stream>>>(x, Wgk1, tmp16);
    gatek_kernel<<<(BT*KD)/256, 256, 0, stream>>>(tmp16, Wgk2, bgk2, gk);
    gateprep_kernel<<<B_*NCH*H_, 128, 0, stream>>>(q, k, gk, glast);

    // GLA
    intra_kernel<<<B_*NCH*H_, 256, 0, stream>>>(q, k, v, o);
    scan_kernel<<<B_*H_*4, 256, 0, stream>>>(q, gk, v, glast, o);

    // epilogue
    normgate_kernel<<<(BT*H_)/4, 256, 0, stream>>>(o, g, gnw);
    gemm_f32<<<dim3(BT/64, VD/64), 256, 0, stream>>>(o, Wo, (float*)d_out, BT, DM, VD);
}

// Round 2
// 532.546 us; speedup vs baseline: 2.8908x; 2.8908x over previous
//
#include <hip/hip_runtime.h>
#include <hip/hip_bf16.h>
#include <stdint.h>

#define B_  4
#define T_  2048
#define DM  1024
#define H_  4
#define DK_ 128
#define DV_ 256
#define KD  512     // H_*DK_
#define VD  1024    // H_*DV_
#define NCH 32      // num chunks
#define CC  64      // chunk len
#define BT  8192    // B_*T_
#define SCALE 0.08838834764831845f   // 1/sqrt(128)
#define GNORM_INV 0.0625f            // 1/16

typedef __attribute__((ext_vector_type(8))) short short8;   // 8 bf16 (4 VGPRs)
typedef __attribute__((ext_vector_type(4))) float f32x4;
typedef uint32_t u32;
typedef unsigned short ushort_t;

__device__ inline ushort_t f2b(float f) {               // f32 -> bf16 RNE
    u32 u = __builtin_bit_cast(u32, f);
    u32 r = (u + 0x7fffu + ((u >> 16) & 1u)) >> 16;
    return (ushort_t)r;
}
__device__ inline float b2f(ushort_t h) {
    return __builtin_bit_cast(float, (u32)h << 16);
}
__device__ inline void unpack2(u32 u, float& lo, float& hi) {
    lo = __builtin_bit_cast(float, u << 16);
    hi = __builtin_bit_cast(float, u & 0xffff0000u);
}

// ---------------------------------------------------------------------------
// cvtx: f32 -> bf16 straight conversion (8 elems/thread)
// ---------------------------------------------------------------------------
__global__ __launch_bounds__(256)
void cvtx(const float* __restrict__ x, ushort_t* __restrict__ xb, int n) {
    int idx = (blockIdx.x * 256 + threadIdx.x) * 8;
    if (idx >= n) return;
    float4 a = *(const float4*)&x[idx];
    float4 b = *(const float4*)&x[idx + 4];
    uint4 p;
    p.x = (u32)f2b(a.x) | ((u32)f2b(a.y) << 16);
    p.y = (u32)f2b(a.z) | ((u32)f2b(a.w) << 16);
    p.z = (u32)f2b(b.x) | ((u32)f2b(b.y) << 16);
    p.w = (u32)f2b(b.z) | ((u32)f2b(b.w) << 16);
    *(uint4*)&xb[idx] = p;
}

// ---------------------------------------------------------------------------
// tcvt: W[K][N] f32 -> Wt[N][K] bf16 (transpose + convert), 32x32 LDS tiles
// ---------------------------------------------------------------------------
__global__ __launch_bounds__(256)
void tcvt(const float* __restrict__ W, ushort_t* __restrict__ Wt, int K, int N) {
    __shared__ float tile[32][33];
    const int k0 = blockIdx.x * 32, n0 = blockIdx.y * 32;
    const int r = threadIdx.x >> 3, c4 = (threadIdx.x & 7) * 4;
    float4 wv = *(const float4*)&W[(size_t)(k0 + r) * N + n0 + c4];
    tile[r][c4 + 0] = wv.x; tile[r][c4 + 1] = wv.y;
    tile[r][c4 + 2] = wv.z; tile[r][c4 + 3] = wv.w;
    __syncthreads();
    u32 lo = (u32)f2b(tile[c4 + 0][r]) | ((u32)f2b(tile[c4 + 1][r]) << 16);
    u32 hi = (u32)f2b(tile[c4 + 2][r]) | ((u32)f2b(tile[c4 + 3][r]) << 16);
    uint2 o2; o2.x = lo; o2.y = hi;
    *(uint2*)&Wt[(size_t)(n0 + r) * K + k0 + c4] = o2;
}

// ---------------------------------------------------------------------------
// bf16 MFMA GEMM: C[M,N] = A[M,K] @ Wt[N,K]^T.  128x128 tile, BK=32, 4 waves.
// OUTBF: 0 -> f32 C, 1 -> bf16 C.
// ---------------------------------------------------------------------------
template<int OUTBF>
__global__ __launch_bounds__(256)
void gemm_bf16(const ushort_t* __restrict__ A, const ushort_t* __restrict__ Bt,
               void* __restrict__ Cout, int M, int N, int K) {
    __shared__ ushort_t Al[128 * 40];   // row stride 40 bf16 = 80B (2-way-free)
    __shared__ ushort_t Bl[128 * 40];
    const int t = threadIdx.x;
    const int wave = t >> 6, lane = t & 63;
    const int wr = wave >> 1, wc = wave & 1;           // 2x2 wave grid, 64x64 each
    const int row0 = blockIdx.x * 128, col0 = blockIdx.y * 128;
    const int lr = t >> 2;                             // staging row 0..63
    const int lk8 = (t & 3) * 8;                       // staging k offset (bf16)
    const int lm = lane & 15, lk = (lane >> 4) * 8;    // fragment indices

    f32x4 acc[4][4];
    #pragma unroll
    for (int i = 0; i < 4; ++i)
        #pragma unroll
        for (int j = 0; j < 4; ++j) acc[i][j] = f32x4{0.f, 0.f, 0.f, 0.f};

    const ushort_t* Ap = A + (size_t)row0 * K;
    const ushort_t* Bp = Bt + (size_t)col0 * K;

    for (int k0 = 0; k0 < K; k0 += 32) {
        __syncthreads();
        #pragma unroll
        for (int m = 0; m < 2; ++m) {
            int r = m * 64 + lr;
            uint4 av = *(const uint4*)(Ap + (size_t)r * K + k0 + lk8);
            *(uint4*)(&Al[r * 40 + lk8]) = av;
            uint4 bv = *(const uint4*)(Bp + (size_t)r * K + k0 + lk8);
            *(uint4*)(&Bl[r * 40 + lk8]) = bv;
        }
        __syncthreads();
        short8 af[4], bfr[4];
        #pragma unroll
        for (int f = 0; f < 4; ++f)
            af[f] = *(const short8*)(&Al[(wr * 64 + f * 16 + lm) * 40 + lk]);
        #pragma unroll
        for (int f = 0; f < 4; ++f)
            bfr[f] = *(const short8*)(&Bl[(wc * 64 + f * 16 + lm) * 40 + lk]);
        #pragma unroll
        for (int i = 0; i < 4; ++i)
            #pragma unroll
            for (int j = 0; j < 4; ++j)
                acc[i][j] = __builtin_amdgcn_mfma_f32_16x16x32_bf16(af[i], bfr[j], acc[i][j], 0, 0, 0);
    }
    // epilogue: D[m][n]: m = (lane>>4)*4+e (+16i +64wr), n = lane&15 (+16j +64wc)
    const int orow = row0 + wr * 64 + (lane >> 4) * 4;
    const int ocol = col0 + wc * 64 + lm;
    #pragma unroll
    for (int i = 0; i < 4; ++i)
        #pragma unroll
        for (int j = 0; j < 4; ++j)
            #pragma unroll
            for (int e = 0; e < 4; ++e) {
                int rr = orow + i * 16 + e, cc = ocol + j * 16;
                if (OUTBF) ((ushort_t*)Cout)[(size_t)rr * N + cc] = f2b(acc[i][j][e]);
                else       ((float*)Cout)[(size_t)rr * N + cc]   = acc[i][j][e];
            }
}

// ---------------------------------------------------------------------------
// Low-rank gate stage 1: tmp[BT,16] = x @ Wgk1   (f32)
// ---------------------------------------------------------------------------
__global__ __launch_bounds__(256)
void lowrank_kernel(const float* __restrict__ x, const float* __restrict__ W1,
                    float* __restrict__ tmp) {
    const int t = threadIdx.x;
    const int r = t >> 4, c = t & 15;
    const int row = blockIdx.x * 16 + r;
    const float* xp = x + (size_t)row * DM;
    float acc = 0.f;
    for (int kk = 0; kk < DM; kk += 4) {
        float4 xv = *(const float4*)(xp + kk);
        acc += xv.x * W1[(kk + 0) * 16 + c];
        acc += xv.y * W1[(kk + 1) * 16 + c];
        acc += xv.z * W1[(kk + 2) * 16 + c];
        acc += xv.w * W1[(kk + 3) * 16 + c];
    }
    tmp[row * 16 + c] = acc;
}

// ---------------------------------------------------------------------------
// Gate stage 2: gk[BT,512] = log_sigmoid(tmp @ Wgk2 + b) / 16
// ---------------------------------------------------------------------------
__global__ __launch_bounds__(256)
void gatek_kernel(const float* __restrict__ tmp, const float* __restrict__ W2,
                  const float* __restrict__ bias, float* __restrict__ gk) {
    const int idx = blockIdx.x * 256 + threadIdx.x;
    const int bt = idx >> 9, c = idx & 511;
    float z = bias[c];
    #pragma unroll
    for (int j = 0; j < 16; ++j)
        z += tmp[bt * 16 + j] * W2[j * KD + c];
    float ls = fminf(z, 0.f) - log1pf(expf(-fabsf(z)));
    gk[idx] = ls * GNORM_INV;
}

// ---------------------------------------------------------------------------
// Gate prep (in place): q->qg, k->k_intra, gk->kg; writes glast.
// ---------------------------------------------------------------------------
__global__ __launch_bounds__(128)
void gateprep_kernel(float* __restrict__ q, float* __restrict__ k,
                     float* __restrict__ gk, float* __restrict__ glast) {
    const int bid = blockIdx.x;
    const int h = bid % H_;
    const int bn = bid / H_;
    const int nc = bn % NCH, b = bn / NCH;
    const int d = threadIdx.x;
    const int t0 = b * T_ + nc * CC;
    const int base = t0 * KD + h * DK_ + d;

    float total = 0.f;
    for (int i = 0; i < CC; ++i) total += gk[base + i * KD];

    float G = 0.f;
    for (int i = 0; i < CC; ++i) {
        const int idx = base + i * KD;
        float gv = gk[idx];
        G += gv;
        float qv = q[idx], kv = k[idx];
        q[idx]  = qv * expf(G) * SCALE;
        k[idx]  = kv * expf(-G);
        gk[idx] = kv * expf(total - G);
    }
    glast[((b * H_ + h) * NCH + nc) * DK_ + d] = expf(total);
}

// ---------------------------------------------------------------------------
// Intra-chunk: A = tril(qg @ k_intra^T); o = A @ v (v in bf16). 512 blocks.
// ---------------------------------------------------------------------------
__global__ __launch_bounds__(256)
void intra_kernel(const float* __restrict__ qg, const float* __restrict__ ki,
                  const ushort_t* __restrict__ vbf, float* __restrict__ o) {
    __shared__ __align__(16) char smem_raw[34816 * 2 + 17408];
    float (*qsT)[68] = (float(*)[68])(smem_raw);
    float (*kiT)[68] = (float(*)[68])(smem_raw + 34816);
    float (*As)[68]  = (float(*)[68])(smem_raw + 69632);
    float (*vs)[260] = (float(*)[260])(smem_raw);          // overlays qsT/kiT

    const int bid = blockIdx.x;
    const int h = bid % H_;
    const int bn = bid / H_;
    const int nc = bn % NCH, b = bn / NCH;
    const int t0 = b * T_ + nc * CC;
    const int t = threadIdx.x;

    #pragma unroll
    for (int m = 0; m < 8; ++m) {
        const int p = t + m * 256;
        const int i = p >> 5;
        const int d4 = (p & 31) * 4;
        const int gidx = (t0 + i) * KD + h * DK_ + d4;
        float4 a = *(const float4*)&qg[gidx];
        qsT[d4 + 0][i] = a.x; qsT[d4 + 1][i] = a.y; qsT[d4 + 2][i] = a.z; qsT[d4 + 3][i] = a.w;
        float4 c = *(const float4*)&ki[gidx];
        kiT[d4 + 0][i] = c.x; kiT[d4 + 1][i] = c.y; kiT[d4 + 2][i] = c.z; kiT[d4 + 3][i] = c.w;
    }
    __syncthreads();

    {
        const int tj = t & 15, ti = t >> 4;
        const int i0 = ti * 4, j0 = tj * 4;
        float a4[4][4];
        #pragma unroll
        for (int r = 0; r < 4; ++r)
            #pragma unroll
            for (int c = 0; c < 4; ++c) a4[r][c] = 0.f;
        for (int d = 0; d < 128; ++d) {
            float4 qv = *(const float4*)&qsT[d][i0];
            float4 kv = *(const float4*)&kiT[d][j0];
            float qr[4] = {qv.x, qv.y, qv.z, qv.w};
            float kr[4] = {kv.x, kv.y, kv.z, kv.w};
            #pragma unroll
            for (int r = 0; r < 4; ++r)
                #pragma unroll
                for (int c = 0; c < 4; ++c)
                    a4[r][c] += qr[r] * kr[c];
        }
        __syncthreads();
        #pragma unroll
        for (int r = 0; r < 4; ++r)
            #pragma unroll
            for (int c = 0; c < 4; ++c)
                As[i0 + r][j0 + c] = (j0 + c <= i0 + r) ? a4[r][c] : 0.f;
    }
    __syncthreads();

    // stage v (bf16 -> f32 LDS), overlays qsT/kiT
    #pragma unroll
    for (int m = 0; m < 8; ++m) {
        const int p = t + m * 256;               // 2048 chunks of 8 bf16
        const int i = p >> 5;
        const int c8 = (p & 31) * 8;
        uint4 raw = *(const uint4*)&vbf[(size_t)(t0 + i) * VD + h * DV_ + c8];
        float f0, f1, f2, f3, f4, f5, f6, f7;
        unpack2(raw.x, f0, f1); unpack2(raw.y, f2, f3);
        unpack2(raw.z, f4, f5); unpack2(raw.w, f6, f7);
        float4 lo4 = {f0, f1, f2, f3}, hi4 = {f4, f5, f6, f7};
        *(float4*)&vs[i][c8] = lo4;
        *(float4*)&vs[i][c8 + 4] = hi4;
    }
    __syncthreads();

    {
        const int dv4 = (t & 63) * 4;
        const int ig = t >> 6;
        for (int r = 0; r < 16; ++r) {
            const int i = ig * 16 + r;
            float4 acc = make_float4(0.f, 0.f, 0.f, 0.f);
            for (int j = 0; j <= i; ++j) {
                float Av = As[i][j];
                float4 vv = *(const float4*)&vs[j][dv4];
                acc.x += Av * vv.x; acc.y += Av * vv.y; acc.z += Av * vv.z; acc.w += Av * vv.w;
            }
            *(float4*)&o[(size_t)(t0 + i) * VD + h * DV_ + dv4] = acc;
        }
    }
}

// ---------------------------------------------------------------------------
// chunk_state: M_c = kg_c^T v_c  (128x256), bf16 out. 512 blocks (bh,c).
// ---------------------------------------------------------------------------
__global__ __launch_bounds__(256)
void chunk_state(const float* __restrict__ kg, const ushort_t* __restrict__ vbf,
                 ushort_t* __restrict__ Sst) {
    __shared__ float kgs[64][132];
    __shared__ ushort_t vsb[64][256];
    const int bid = blockIdx.x;
    const int c = bid & 31, bh = bid >> 5;
    const int b = bh >> 2, h = bh & 3;
    const int t0 = b * T_ + c * CC;
    const int t = threadIdx.x;

    #pragma unroll
    for (int m = 0; m < 8; ++m) {
        int p = t + m * 256; int i = p >> 5; int d4 = (p & 31) * 4;
        *(float4*)&kgs[i][d4] = *(const float4*)&kg[(size_t)(t0 + i) * KD + h * DK_ + d4];
    }
    #pragma unroll
    for (int m = 0; m < 8; ++m) {
        int p = t + m * 256; int i = p >> 5; int c8 = (p & 31) * 8;
        *(uint4*)&vsb[i][c8] = *(const uint4*)&vbf[(size_t)(t0 + i) * VD + h * DV_ + c8];
    }
    __syncthreads();

    const int dk0 = (t >> 4) * 8;
    const int dv0 = (t & 15) * 16;
    float acc[8][16];
    #pragma unroll
    for (int dd = 0; dd < 8; ++dd)
        #pragma unroll
        for (int e = 0; e < 16; ++e) acc[dd][e] = 0.f;

    for (int j = 0; j < 64; ++j) {
        float kv[8];
        *(float4*)&kv[0] = *(const float4*)&kgs[j][dk0];
        *(float4*)&kv[4] = *(const float4*)&kgs[j][dk0 + 4];
        uint4 r0 = *(const uint4*)&vsb[j][dv0];
        uint4 r1 = *(const uint4*)&vsb[j][dv0 + 8];
        float vv[16];
        unpack2(r0.x, vv[0], vv[1]);  unpack2(r0.y, vv[2], vv[3]);
        unpack2(r0.z, vv[4], vv[5]);  unpack2(r0.w, vv[6], vv[7]);
        unpack2(r1.x, vv[8], vv[9]);  unpack2(r1.y, vv[10], vv[11]);
        unpack2(r1.z, vv[12], vv[13]); unpack2(r1.w, vv[14], vv[15]);
        #pragma unroll
        for (int dd = 0; dd < 8; ++dd)
            #pragma unroll
            for (int e = 0; e < 16; ++e)
                acc[dd][e] += kv[dd] * vv[e];
    }

    const size_t base = (size_t)bid * (DK_ * DV_);
    #pragma unroll
    for (int dd = 0; dd < 8; ++dd) {
        u32 w[8];
        #pragma unroll
        for (int e = 0; e < 8; ++e)
            w[e] = (u32)f2b(acc[dd][2 * e]) | ((u32)f2b(acc[dd][2 * e + 1]) << 16);
        ushort_t* dst = &Sst[base + (size_t)(dk0 + dd) * DV_ + dv0];
        *(uint4*)dst = make_uint4(w[0], w[1], w[2], w[3]);
        *(uint4*)(dst + 8) = make_uint4(w[4], w[5], w[6], w[7]);
    }
}

// ---------------------------------------------------------------------------
// scan_combine: in-place convert M_c -> exclusive prefix P_c.
// P_{c+1} = gl_c (x) P_c + M_c.  128 blocks (bh, dvtile of 32).
// ---------------------------------------------------------------------------
__global__ __launch_bounds__(256)
void scan_combine(ushort_t* __restrict__ Sst, const float* __restrict__ glast) {
    const int bid = blockIdx.x;
    const int dvt = bid & 7, bh = bid >> 3;
    const int t = threadIdx.x;
    const int dk = t >> 1, dv0 = dvt * 32 + (t & 1) * 16;

    float P[16];
    #pragma unroll
    for (int e = 0; e < 16; ++e) P[e] = 0.f;

    for (int c = 0; c < NCH; ++c) {
        const size_t base = (size_t)(bh * NCH + c) * (DK_ * DV_) + (size_t)dk * DV_ + dv0;
        uint4 m0 = *(const uint4*)&Sst[base];
        uint4 m1 = *(const uint4*)&Sst[base + 8];
        // write exclusive prefix
        u32 w[8];
        #pragma unroll
        for (int e = 0; e < 8; ++e)
            w[e] = (u32)f2b(P[2 * e]) | ((u32)f2b(P[2 * e + 1]) << 16);
        *(uint4*)&Sst[base] = make_uint4(w[0], w[1], w[2], w[3]);
        *(uint4*)&Sst[base + 8] = make_uint4(w[4], w[5], w[6], w[7]);
        // advance
        float mv[16];
        unpack2(m0.x, mv[0], mv[1]);  unpack2(m0.y, mv[2], mv[3]);
        unpack2(m0.z, mv[4], mv[5]);  unpack2(m0.w, mv[6], mv[7]);
        unpack2(m1.x, mv[8], mv[9]);  unpack2(m1.y, mv[10], mv[11]);
        unpack2(m1.z, mv[12], mv[13]); unpack2(m1.w, mv[14], mv[15]);
        const float gl = glast[(size_t)(bh * NCH + c) * DK_ + dk];
        #pragma unroll
        for (int e = 0; e < 16; ++e) P[e] = gl * P[e] + mv[e];
    }
}

// ---------------------------------------------------------------------------
// ointer: o[64x256] += qg[64x128] @ P[128x256].  512 blocks (bh,c).
// ---------------------------------------------------------------------------
__global__ __launch_bounds__(256)
void ointer(const float* __restrict__ qg, const ushort_t* __restrict__ Sst,
            float* __restrict__ o) {
    __shared__ float qs[64][132];
    __shared__ ushort_t Ps[128 * 256];
    const int bid = blockIdx.x;
    const int c = bid & 31, bh = bid >> 5;
    const int b = bh >> 2, h = bh & 3;
    const int t0 = b * T_ + c * CC;
    const int t = threadIdx.x;

    #pragma unroll
    for (int m = 0; m < 8; ++m) {
        int p = t + m * 256; int i = p >> 5; int d4 = (p & 31) * 4;
        *(float4*)&qs[i][d4] = *(const float4*)&qg[(size_t)(t0 + i) * KD + h * DK_ + d4];
    }
    const size_t sbase = (size_t)bid * (DK_ * DV_);
    #pragma unroll
    for (int m = 0; m < 16; ++m) {
        int p = t + m * 256;                      // 4096 chunks of 8 bf16
        *(uint4*)&Ps[p * 8] = *(const uint4*)&Sst[sbase + (size_t)p * 8];
    }
    __syncthreads();

    const int rg = t >> 4;                        // 0..15
    const int dv0 = (t & 15) * 16;
    float acc[4][16];
    #pragma unroll
    for (int i2 = 0; i2 < 4; ++i2)
        #pragma unroll
        for (int e = 0; e < 16; ++e) acc[i2][e] = 0.f;

    for (int d = 0; d < 128; ++d) {
        float qv[4];
        #pragma unroll
        for (int i2 = 0; i2 < 4; ++i2) qv[i2] = qs[rg + 16 * i2][d];
        uint4 r0 = *(const uint4*)&Ps[d * 256 + dv0];
        uint4 r1 = *(const uint4*)&Ps[d * 256 + dv0 + 8];
        float vv[16];
        unpack2(r0.x, vv[0], vv[1]);  unpack2(r0.y, vv[2], vv[3]);
        unpack2(r0.z, vv[4], vv[5]);  unpack2(r0.w, vv[6], vv[7]);
        unpack2(r1.x, vv[8], vv[9]);  unpack2(r1.y, vv[10], vv[11]);
        unpack2(r1.z, vv[12], vv[13]); unpack2(r1.w, vv[14], vv[15]);
        #pragma unroll
        for (int i2 = 0; i2 < 4; ++i2)
            #pragma unroll
            for (int e = 0; e < 16; ++e)
                acc[i2][e] += qv[i2] * vv[e];
    }

    #pragma unroll
    for (int i2 = 0; i2 < 4; ++i2) {
        const int row = rg + 16 * i2;
        float* op = &o[(size_t)(t0 + row) * VD + h * DV_ + dv0];
        #pragma unroll
        for (int e4 = 0; e4 < 4; ++e4) {
            float4 cur = *(float4*)&op[e4 * 4];
            cur.x += acc[i2][e4 * 4 + 0];
            cur.y += acc[i2][e4 * 4 + 1];
            cur.z += acc[i2][e4 * 4 + 2];
            cur.w += acc[i2][e4 * 4 + 3];
            *(float4*)&op[e4 * 4] = cur;
        }
    }
}

// ---------------------------------------------------------------------------
// normgate: obf = bf16( RMSNorm(o)*gnw * swish(g) ).  One wave per row.
// ---------------------------------------------------------------------------
__global__ __launch_bounds__(256)
void normgate_kernel(const float* __restrict__ o, const ushort_t* __restrict__ gbf,
                     const float* __restrict__ gnw, ushort_t* __restrict__ obf) {
    const int t = threadIdx.x;
    const int w = t >> 6, lane = t & 63;
    const int row = blockIdx.x * 4 + w;           // over BT*H_
    const size_t base = (size_t)row * DV_ + lane * 4;

    float4 ov = *(const float4*)&o[base];
    float ssq = ov.x * ov.x + ov.y * ov.y + ov.z * ov.z + ov.w * ov.w;
    #pragma unroll
    for (int off = 32; off > 0; off >>= 1) ssq += __shfl_xor(ssq, off);
    const float rms = rsqrtf(ssq * (1.0f / DV_) + 1e-5f);

    uint2 gv2 = *(const uint2*)&gbf[base];
    float g0, g1, g2, g3;
    unpack2(gv2.x, g0, g1); unpack2(gv2.y, g2, g3);
    float4 wv = *(const float4*)&gnw[lane * 4];
    float o0 = ov.x * rms * wv.x * (g0 / (1.f + expf(-g0)));
    float o1 = ov.y * rms * wv.y * (g1 / (1.f + expf(-g1)));
    float o2 = ov.z * rms * wv.z * (g2 / (1.f + expf(-g2)));
    float o3 = ov.w * rms * wv.w * (g3 / (1.f + expf(-g3)));
    uint2 p;
    p.x = (u32)f2b(o0) | ((u32)f2b(o1) << 16);
    p.y = (u32)f2b(o2) | ((u32)f2b(o3) << 16);
    *(uint2*)&obf[base] = p;
}

// ---------------------------------------------------------------------------
extern "C" void kernel_launch(void* const* d_in, const int* in_sizes, int n_in,
                              void* d_out, int out_size, void* d_ws, size_t ws_size,
                              hipStream_t stream) {
    const float* x    = (const float*)d_in[0];
    const float* Wq   = (const float*)d_in[1];
    const float* Wk   = (const float*)d_in[2];
    const float* Wv   = (const float*)d_in[3];
    const float* Wg   = (const float*)d_in[4];
    const float* Wgk1 = (const float*)d_in[5];
    const float* Wgk2 = (const float*)d_in[6];
    const float* bgk2 = (const float*)d_in[7];
    const float* Wo   = (const float*)d_in[8];
    const float* gnw  = (const float*)d_in[9];

    float* ws = (float*)d_ws;
    // f32 regions (float offsets)
    float* q      = ws;                           // [0, 4.19M)  BT*KD f32 (-> qg)
    float* kbuf   = ws + 4194304;                 // BT*KD f32 (-> k_intra); later gbf
    float* gk     = ws + 8388608;                 // BT*KD f32 (kg); wbfA early
    ushort_t* vbf = (ushort_t*)(ws + 12582912);   // BT*VD bf16
    ushort_t* Sst = (ushort_t*)(ws + 16777216);   // states 16.78M bf16 (33.55MB); wbfB early; obf late
    float* o      = ws + 25165824;                // BT*VD f32
    ushort_t* xbf = (ushort_t*)(ws + 33554432);   // BT*DM bf16
    float* tmp16  = ws + 37748736;                // BT*16
    float* glast  = ws + 37879808;                // B*H*NCH*DK f32
    // transient weight slots
    ushort_t* wbfA = (ushort_t*)gk;               // inside gk region (pre-gate)
    ushort_t* wbfB = (ushort_t*)Sst;              // inside states (pre-chunk_state)
    ushort_t* wbfC = (ushort_t*)(ws + 16777216 + 4194304); // states+4.19M f (post-ointer)
    ushort_t* gbf  = (ushort_t*)kbuf;             // k region after intra
    ushort_t* obf  = Sst;                         // states region after ointer

    // x -> bf16
    cvtx<<<BT * DM / 2048, 256, 0, stream>>>(x, xbf, BT * DM);

    // projections (bf16 MFMA)
    tcvt<<<dim3(32, 16), 256, 0, stream>>>(Wq, wbfA, DM, KD);
    gemm_bf16<0><<<dim3(64, 4), 256, 0, stream>>>(xbf, wbfA, q, BT, KD, DM);
    tcvt<<<dim3(32, 16), 256, 0, stream>>>(Wk, wbfA, DM, KD);
    gemm_bf16<0><<<dim3(64, 4), 256, 0, stream>>>(xbf, wbfA, kbuf, BT, KD, DM);
    tcvt<<<dim3(32, 32), 256, 0, stream>>>(Wv, wbfA, DM, VD);
    gemm_bf16<1><<<dim3(64, 8), 256, 0, stream>>>(xbf, wbfA, vbf, BT, VD, DM);

    // gate path (f32, reads pristine x)
    lowrank_kernel<<<BT / 16, 256, 0, stream>>>(x, Wgk1, tmp16);
    gatek_kernel<<<(BT * KD) / 256, 256, 0, stream>>>(tmp16, Wgk2, bgk2, gk);
    gateprep_kernel<<<B_ * NCH * H_, 128, 0, stream>>>(q, kbuf, gk, glast);

    // intra-chunk (k_intra consumed here)
    intra_kernel<<<B_ * NCH * H_, 256, 0, stream>>>(q, kbuf, vbf, o);

    // g projection into freed k region (bf16 out)
    tcvt<<<dim3(32, 32), 256, 0, stream>>>(Wg, wbfB, DM, VD);
    gemm_bf16<1><<<dim3(64, 8), 256, 0, stream>>>(xbf, wbfB, gbf, BT, VD, DM);

    // inter-chunk: parallel states -> cheap scan -> parallel apply
    chunk_state<<<512, 256, 0, stream>>>(gk, vbf, Sst);
    scan_combine<<<128, 256, 0, stream>>>(Sst, glast);
    ointer<<<512, 256, 0, stream>>>(q, Sst, o);

    // epilogue
    tcvt<<<dim3(32, 32), 256, 0, stream>>>(Wo, wbfC, VD, DM);
    normgate_kernel<<<(BT * H_) / 4, 256, 0, stream>>>(o, gbf, gnw, obf);
    gemm_bf16<0><<<dim3(64, 8), 256, 0, stream>>>(obf, wbfC, (float*)d_out, BT, DM, VD);
}

// Round 3
// 412.140 us; speedup vs baseline: 3.7354x; 1.2921x over previous
//
#include <hip/hip_runtime.h>
#include <hip/hip_bf16.h>
#include <stdint.h>

#define B_  4
#define T_  2048
#define DM  1024
#define H_  4
#define DK_ 128
#define DV_ 256
#define KD  512     // H_*DK_
#define VD  1024    // H_*DV_
#define NCH 32      // num chunks
#define CC  64      // chunk len
#define BT  8192    // B_*T_
#define SCALE 0.08838834764831845f   // 1/sqrt(128)
#define GNORM_INV 0.0625f            // 1/16

typedef __attribute__((ext_vector_type(8))) short short8;   // 8 bf16 (4 VGPRs)
typedef __attribute__((ext_vector_type(4))) float f32x4;
typedef uint32_t u32;
typedef unsigned short ushort_t;

__device__ inline ushort_t f2b(float f) {               // f32 -> bf16 RNE
    u32 u = __builtin_bit_cast(u32, f);
    u32 r = (u + 0x7fffu + ((u >> 16) & 1u)) >> 16;
    return (ushort_t)r;
}
__device__ inline void unpack2(u32 u, float& lo, float& hi) {
    lo = __builtin_bit_cast(float, u << 16);
    hi = __builtin_bit_cast(float, u & 0xffff0000u);
}

// ---------------------------------------------------------------------------
// cvtx: f32 -> bf16 straight conversion (8 elems/thread)
// ---------------------------------------------------------------------------
__global__ __launch_bounds__(256)
void cvtx(const float* __restrict__ x, ushort_t* __restrict__ xb, int n) {
    int idx = (blockIdx.x * 256 + threadIdx.x) * 8;
    if (idx >= n) return;
    float4 a = *(const float4*)&x[idx];
    float4 b = *(const float4*)&x[idx + 4];
    uint4 p;
    p.x = (u32)f2b(a.x) | ((u32)f2b(a.y) << 16);
    p.y = (u32)f2b(a.z) | ((u32)f2b(a.w) << 16);
    p.z = (u32)f2b(b.x) | ((u32)f2b(b.y) << 16);
    p.w = (u32)f2b(b.z) | ((u32)f2b(b.w) << 16);
    *(uint4*)&xb[idx] = p;
}

// ---------------------------------------------------------------------------
// tcvt: W[K][N] f32 -> Wt[N][K] bf16 (transpose + convert), 32x32 LDS tiles
// ---------------------------------------------------------------------------
__global__ __launch_bounds__(256)
void tcvt(const float* __restrict__ W, ushort_t* __restrict__ Wt, int K, int N) {
    __shared__ float tile[32][33];
    const int k0 = blockIdx.x * 32, n0 = blockIdx.y * 32;
    const int r = threadIdx.x >> 3, c4 = (threadIdx.x & 7) * 4;
    float4 wv = *(const float4*)&W[(size_t)(k0 + r) * N + n0 + c4];
    tile[r][c4 + 0] = wv.x; tile[r][c4 + 1] = wv.y;
    tile[r][c4 + 2] = wv.z; tile[r][c4 + 3] = wv.w;
    __syncthreads();
    u32 lo = (u32)f2b(tile[c4 + 0][r]) | ((u32)f2b(tile[c4 + 1][r]) << 16);
    u32 hi = (u32)f2b(tile[c4 + 2][r]) | ((u32)f2b(tile[c4 + 3][r]) << 16);
    uint2 o2; o2.x = lo; o2.y = hi;
    *(uint2*)&Wt[(size_t)(n0 + r) * K + k0 + c4] = o2;
}

// ---------------------------------------------------------------------------
// bf16 MFMA GEMM: C[M,N] = A[M,K] @ Wt[N,K]^T.  128x128 tile, BK=32, 4 waves.
// ---------------------------------------------------------------------------
template<int OUTBF>
__global__ __launch_bounds__(256)
void gemm_bf16(const ushort_t* __restrict__ A, const ushort_t* __restrict__ Bt,
               void* __restrict__ Cout, int M, int N, int K) {
    __shared__ ushort_t Al[128 * 40];
    __shared__ ushort_t Bl[128 * 40];
    const int t = threadIdx.x;
    const int wave = t >> 6, lane = t & 63;
    const int wr = wave >> 1, wc = wave & 1;
    const int row0 = blockIdx.x * 128, col0 = blockIdx.y * 128;
    const int lr = t >> 2;
    const int lk8 = (t & 3) * 8;
    const int lm = lane & 15, lk = (lane >> 4) * 8;

    f32x4 acc[4][4];
    #pragma unroll
    for (int i = 0; i < 4; ++i)
        #pragma unroll
        for (int j = 0; j < 4; ++j) acc[i][j] = f32x4{0.f, 0.f, 0.f, 0.f};

    const ushort_t* Ap = A + (size_t)row0 * K;
    const ushort_t* Bp = Bt + (size_t)col0 * K;

    for (int k0 = 0; k0 < K; k0 += 32) {
        __syncthreads();
        #pragma unroll
        for (int m = 0; m < 2; ++m) {
            int r = m * 64 + lr;
            uint4 av = *(const uint4*)(Ap + (size_t)r * K + k0 + lk8);
            *(uint4*)(&Al[r * 40 + lk8]) = av;
            uint4 bv = *(const uint4*)(Bp + (size_t)r * K + k0 + lk8);
            *(uint4*)(&Bl[r * 40 + lk8]) = bv;
        }
        __syncthreads();
        short8 af[4], bfr[4];
        #pragma unroll
        for (int f = 0; f < 4; ++f)
            af[f] = *(const short8*)(&Al[(wr * 64 + f * 16 + lm) * 40 + lk]);
        #pragma unroll
        for (int f = 0; f < 4; ++f)
            bfr[f] = *(const short8*)(&Bl[(wc * 64 + f * 16 + lm) * 40 + lk]);
        #pragma unroll
        for (int i = 0; i < 4; ++i)
            #pragma unroll
            for (int j = 0; j < 4; ++j)
                acc[i][j] = __builtin_amdgcn_mfma_f32_16x16x32_bf16(af[i], bfr[j], acc[i][j], 0, 0, 0);
    }
    const int orow = row0 + wr * 64 + (lane >> 4) * 4;
    const int ocol = col0 + wc * 64 + lm;
    #pragma unroll
    for (int i = 0; i < 4; ++i)
        #pragma unroll
        for (int j = 0; j < 4; ++j)
            #pragma unroll
            for (int e = 0; e < 4; ++e) {
                int rr = orow + i * 16 + e, cc = ocol + j * 16;
                if (OUTBF) ((ushort_t*)Cout)[(size_t)rr * N + cc] = f2b(acc[i][j][e]);
                else       ((float*)Cout)[(size_t)rr * N + cc]   = acc[i][j][e];
            }
}

// ---------------------------------------------------------------------------
// Low-rank gate stage 1: tmp[BT,16] = x @ Wgk1   (f32)
// ---------------------------------------------------------------------------
__global__ __launch_bounds__(256)
void lowrank_kernel(const float* __restrict__ x, const float* __restrict__ W1,
                    float* __restrict__ tmp) {
    const int t = threadIdx.x;
    const int r = t >> 4, c = t & 15;
    const int row = blockIdx.x * 16 + r;
    const float* xp = x + (size_t)row * DM;
    float acc = 0.f;
    for (int kk = 0; kk < DM; kk += 4) {
        float4 xv = *(const float4*)(xp + kk);
        acc += xv.x * W1[(kk + 0) * 16 + c];
        acc += xv.y * W1[(kk + 1) * 16 + c];
        acc += xv.z * W1[(kk + 2) * 16 + c];
        acc += xv.w * W1[(kk + 3) * 16 + c];
    }
    tmp[row * 16 + c] = acc;
}

// ---------------------------------------------------------------------------
// Gate stage 2: gk[BT,512] = log_sigmoid(tmp @ Wgk2 + b) / 16
// ---------------------------------------------------------------------------
__global__ __launch_bounds__(256)
void gatek_kernel(const float* __restrict__ tmp, const float* __restrict__ W2,
                  const float* __restrict__ bias, float* __restrict__ gk) {
    const int idx = blockIdx.x * 256 + threadIdx.x;
    const int bt = idx >> 9, c = idx & 511;
    float z = bias[c];
    #pragma unroll
    for (int j = 0; j < 16; ++j)
        z += tmp[bt * 16 + j] * W2[j * KD + c];
    float ls = fminf(z, 0.f) - log1pf(expf(-fabsf(z)));
    gk[idx] = ls * GNORM_INV;
}

// ---------------------------------------------------------------------------
// gateprep: q,k,gk (f32, [bt][KD]) -> qgb,kib,kgb (bf16, per-chunk [64][128])
// block = (bh,c), 128 thr (one per dk channel)
// ---------------------------------------------------------------------------
__global__ __launch_bounds__(128)
void gateprep_kernel(const float* __restrict__ q, const float* __restrict__ kf,
                     const float* __restrict__ gk,
                     ushort_t* __restrict__ qgb, ushort_t* __restrict__ kib,
                     ushort_t* __restrict__ kgb, float* __restrict__ glast) {
    const int bid = blockIdx.x;
    const int c = bid & 31, bh = bid >> 5;
    const int b = bh >> 2, h = bh & 3;
    const int d = threadIdx.x;
    const int t0 = b * T_ + c * CC;
    const int gbase = t0 * KD + h * DK_ + d;
    const int obase = bid * (CC * DK_) + d;

    float total = 0.f;
    for (int i = 0; i < CC; ++i) total += gk[gbase + i * KD];

    float G = 0.f;
    for (int i = 0; i < CC; ++i) {
        const int gi = gbase + i * KD;
        G += gk[gi];
        float qv = q[gi], kv = kf[gi];
        qgb[obase + i * DK_] = f2b(qv * expf(G) * SCALE);
        kib[obase + i * DK_] = f2b(kv * expf(-G));
        kgb[obase + i * DK_] = f2b(kv * expf(total - G));
    }
    glast[bid * DK_ + d] = expf(total);
}

// ---------------------------------------------------------------------------
// vtrans: vbf [bt][VD] -> vT per-chunk [dv=256][j=64].  block=(bh,c)
// ---------------------------------------------------------------------------
__global__ __launch_bounds__(256)
void vtrans_kernel(const ushort_t* __restrict__ vbf, ushort_t* __restrict__ vT) {
    __shared__ ushort_t vl[64][264];    // stride 264 u16 = 528B (16B-aligned)
    const int bid = blockIdx.x;
    const int c = bid & 31, bh = bid >> 5;
    const int b = bh >> 2, h = bh & 3;
    const int t0 = b * T_ + c * CC;
    const int t = threadIdx.x;

    #pragma unroll
    for (int m = 0; m < 8; ++m) {
        int p = t + m * 256;                 // 2048 uint4
        int j = p >> 5, d8 = (p & 31) * 8;
        *(uint4*)&vl[j][d8] = *(const uint4*)&vbf[(size_t)(t0 + j) * VD + h * DV_ + d8];
    }
    __syncthreads();

    const size_t outb = (size_t)bid * (256 * 64);
    #pragma unroll
    for (int it = 0; it < 2; ++it) {
        int dv = it * 128 + (t >> 1);
        int j0 = (t & 1) * 32;
        u32 vv[16];
        #pragma unroll
        for (int wi = 0; wi < 16; ++wi)
            vv[wi] = (u32)vl[j0 + 2 * wi][dv] | ((u32)vl[j0 + 2 * wi + 1][dv] << 16);
        ushort_t* dst = &vT[outb + (size_t)dv * 64 + j0];
        *(uint4*)(dst + 0)  = make_uint4(vv[0], vv[1], vv[2], vv[3]);
        *(uint4*)(dst + 8)  = make_uint4(vv[4], vv[5], vv[6], vv[7]);
        *(uint4*)(dst + 16) = make_uint4(vv[8], vv[9], vv[10], vv[11]);
        *(uint4*)(dst + 24) = make_uint4(vv[12], vv[13], vv[14], vv[15]);
    }
}

// ---------------------------------------------------------------------------
// chunk_state (MFMA): Sst^T[dv=256][dk=128] = vT(256x64) @ kg(64x128)
// block=(bh,c), 256 thr, 4 waves; B-operand kg^T staged via LDS transpose.
// ---------------------------------------------------------------------------
__global__ __launch_bounds__(256)
void chunk_state(const ushort_t* __restrict__ kgb, const ushort_t* __restrict__ vT,
                 ushort_t* __restrict__ Sst) {
    __shared__ ushort_t kgT[128 * 72];      // [dk][j], stride 72 u16 = 144B
    const int bid = blockIdx.x;
    const int t = threadIdx.x;
    const size_t kgbase = (size_t)bid * (CC * DK_);
    const size_t vtbase = (size_t)bid * (256 * 64);
    const size_t sbase  = (size_t)bid * (256 * 128);

    #pragma unroll
    for (int m = 0; m < 4; ++m) {
        int p = t + m * 256;                 // 1024 uint4
        int j = p >> 4, d0 = (p & 15) * 8;
        uint4 r = *(const uint4*)&kgb[kgbase + (size_t)j * DK_ + d0];
        kgT[(d0 + 0) * 72 + j] = (ushort_t)(r.x & 0xffff);
        kgT[(d0 + 1) * 72 + j] = (ushort_t)(r.x >> 16);
        kgT[(d0 + 2) * 72 + j] = (ushort_t)(r.y & 0xffff);
        kgT[(d0 + 3) * 72 + j] = (ushort_t)(r.y >> 16);
        kgT[(d0 + 4) * 72 + j] = (ushort_t)(r.z & 0xffff);
        kgT[(d0 + 5) * 72 + j] = (ushort_t)(r.z >> 16);
        kgT[(d0 + 6) * 72 + j] = (ushort_t)(r.w & 0xffff);
        kgT[(d0 + 7) * 72 + j] = (ushort_t)(r.w >> 16);
    }
    __syncthreads();

    const int w = t >> 6, lane = t & 63;
    const int lm = lane & 15, lg = lane >> 4;
    #pragma unroll
    for (int mm = 0; mm < 4; ++mm) {
        const int mt = w * 4 + mm;           // dv 16-block
        short8 a0 = *(const short8*)&vT[vtbase + (size_t)(mt * 16 + lm) * 64 + lg * 8];
        short8 a1 = *(const short8*)&vT[vtbase + (size_t)(mt * 16 + lm) * 64 + 32 + lg * 8];
        #pragma unroll
        for (int n = 0; n < 8; ++n) {
            f32x4 acc = {0.f, 0.f, 0.f, 0.f};
            short8 b0 = *(const short8*)&kgT[(n * 16 + lm) * 72 + lg * 8];
            short8 b1 = *(const short8*)&kgT[(n * 16 + lm) * 72 + 32 + lg * 8];
            acc = __builtin_amdgcn_mfma_f32_16x16x32_bf16(a0, b0, acc, 0, 0, 0);
            acc = __builtin_amdgcn_mfma_f32_16x16x32_bf16(a1, b1, acc, 0, 0, 0);
            #pragma unroll
            for (int e = 0; e < 4; ++e)
                Sst[sbase + (size_t)(mt * 16 + lg * 4 + e) * 128 + n * 16 + lm] = f2b(acc[e]);
        }
    }
}

// ---------------------------------------------------------------------------
// scan_combine: in-place M_c -> exclusive prefix P_c over the [dv][dk] states.
// P_{c+1}[dv][dk] = gl_c[dk]*P_c + M_c.  128 blocks (bh, dv-eighth).
// ---------------------------------------------------------------------------
__global__ __launch_bounds__(256)
void scan_combine(ushort_t* __restrict__ Sst, const float* __restrict__ glast) {
    const int bid = blockIdx.x;
    const int dvt = bid & 7, bh = bid >> 3;
    const int t = threadIdx.x;
    const int dv = dvt * 32 + (t >> 3);
    const int dk0 = (t & 7) * 16;

    float P[16];
    #pragma unroll
    for (int e = 0; e < 16; ++e) P[e] = 0.f;

    for (int c = 0; c < NCH; ++c) {
        const size_t base = ((size_t)(bh * NCH + c) * 256 + dv) * 128 + dk0;
        uint4 m0 = *(const uint4*)&Sst[base];
        uint4 m1 = *(const uint4*)&Sst[base + 8];
        u32 wd[8];
        #pragma unroll
        for (int e = 0; e < 8; ++e)
            wd[e] = (u32)f2b(P[2 * e]) | ((u32)f2b(P[2 * e + 1]) << 16);
        *(uint4*)&Sst[base]     = make_uint4(wd[0], wd[1], wd[2], wd[3]);
        *(uint4*)&Sst[base + 8] = make_uint4(wd[4], wd[5], wd[6], wd[7]);
        float mv[16];
        unpack2(m0.x, mv[0], mv[1]);   unpack2(m0.y, mv[2], mv[3]);
        unpack2(m0.z, mv[4], mv[5]);   unpack2(m0.w, mv[6], mv[7]);
        unpack2(m1.x, mv[8], mv[9]);   unpack2(m1.y, mv[10], mv[11]);
        unpack2(m1.z, mv[12], mv[13]); unpack2(m1.w, mv[14], mv[15]);
        const float* glp = &glast[(size_t)(bh * NCH + c) * DK_ + dk0];
        float4 g0 = *(const float4*)&glp[0];
        float4 g1 = *(const float4*)&glp[4];
        float4 g2 = *(const float4*)&glp[8];
        float4 g3 = *(const float4*)&glp[12];
        float gl[16] = {g0.x, g0.y, g0.z, g0.w, g1.x, g1.y, g1.z, g1.w,
                        g2.x, g2.y, g2.z, g2.w, g3.x, g3.y, g3.z, g3.w};
        #pragma unroll
        for (int e = 0; e < 16; ++e) P[e] = gl[e] * P[e] + mv[e];
    }
}

// ---------------------------------------------------------------------------
// fused_chunk (MFMA): o = tril(qg@ki^T)@v + qg@P, all per chunk. 512 blocks.
// LDS: stg (ki 64x[168] then per-quarter S 64x[168]) + vq 64x[104] + A 64x[104]
// ---------------------------------------------------------------------------
__global__ __launch_bounds__(256)
void fused_chunk(const ushort_t* __restrict__ qgb, const ushort_t* __restrict__ kib,
                 const ushort_t* __restrict__ vT, const ushort_t* __restrict__ Sst,
                 float* __restrict__ o) {
    __shared__ __align__(16) ushort_t lds[24064];   // 48.1KB
    ushort_t* stg = lds;                 // [64][168]
    ushort_t* vq  = lds + 10752;         // [64][104]
    ushort_t* Al  = lds + 17408;         // [64][104]

    const int bid = blockIdx.x;
    const int c = bid & 31, bh = bid >> 5;
    const int b = bh >> 2, h = bh & 3;
    const int t0 = b * T_ + c * CC;
    const int t = threadIdx.x;
    const int w = t >> 6, lane = t & 63;
    const int lm = lane & 15, lg = lane >> 4;
    const int m0 = w * 16;

    const size_t qbase  = (size_t)bid * (CC * DK_);
    const size_t vtbase = (size_t)bid * (256 * 64);
    const size_t sbase  = (size_t)bid * (256 * 128);

    // qg A-fragments (rows m0..m0+16, K=128) straight from global; reused twice
    short8 qf[4];
    #pragma unroll
    for (int kk = 0; kk < 4; ++kk)
        qf[kk] = *(const short8*)&qgb[qbase + (size_t)(m0 + lm) * DK_ + kk * 32 + lg * 8];

    // stage ki [64][128] -> stg
    #pragma unroll
    for (int m = 0; m < 4; ++m) {
        int p = t + m * 256;
        int j = p >> 4, d0 = (p & 15) * 8;
        *(uint4*)&stg[j * 168 + d0] = *(const uint4*)&kib[qbase + (size_t)j * DK_ + d0];
    }
    __syncthreads();

    // QK^T: wave w computes rows m0..m0+16 x all 64 cols
    f32x4 accA[4];
    #pragma unroll
    for (int jt = 0; jt < 4; ++jt) accA[jt] = f32x4{0.f, 0.f, 0.f, 0.f};
    #pragma unroll
    for (int jt = 0; jt < 4; ++jt)
        #pragma unroll
        for (int kk = 0; kk < 4; ++kk) {
            short8 bfrag = *(const short8*)&stg[(jt * 16 + lm) * 168 + kk * 32 + lg * 8];
            accA[jt] = __builtin_amdgcn_mfma_f32_16x16x32_bf16(qf[kk], bfrag, accA[jt], 0, 0, 0);
        }
    // tril mask + bf16 -> Al
    #pragma unroll
    for (int jt = 0; jt < 4; ++jt)
        #pragma unroll
        for (int e = 0; e < 4; ++e) {
            int i = m0 + lg * 4 + e, j = jt * 16 + lm;
            Al[i * 104 + j] = f2b(j <= i ? accA[jt][e] : 0.f);
        }
    __syncthreads();

    // A-fragments (K = j = 64)
    short8 af[2];
    #pragma unroll
    for (int kk = 0; kk < 2; ++kk)
        af[kk] = *(const short8*)&Al[(m0 + lm) * 104 + kk * 32 + lg * 8];

    // quarters of dv: o[64 x 64q] = A@v_q + qg@P_q
    #pragma unroll 1
    for (int qq = 0; qq < 4; ++qq) {
        #pragma unroll
        for (int m = 0; m < 2; ++m) {          // vT quarter: 64 rows x 64
            int p = t + m * 256;
            int dvr = p >> 3, d0 = (p & 7) * 8;
            *(uint4*)&vq[dvr * 104 + d0] =
                *(const uint4*)&vT[vtbase + (size_t)(qq * 64 + dvr) * 64 + d0];
        }
        #pragma unroll
        for (int m = 0; m < 4; ++m) {          // Sst quarter: 64 rows x 128
            int p = t + m * 256;
            int dvr = p >> 4, d0 = (p & 15) * 8;
            *(uint4*)&stg[dvr * 168 + d0] =
                *(const uint4*)&Sst[sbase + (size_t)(qq * 64 + dvr) * 128 + d0];
        }
        __syncthreads();
        #pragma unroll
        for (int n = 0; n < 4; ++n) {
            f32x4 acc = {0.f, 0.f, 0.f, 0.f};
            #pragma unroll
            for (int kk = 0; kk < 2; ++kk) {
                short8 bfrag = *(const short8*)&vq[(n * 16 + lm) * 104 + kk * 32 + lg * 8];
                acc = __builtin_amdgcn_mfma_f32_16x16x32_bf16(af[kk], bfrag, acc, 0, 0, 0);
            }
            #pragma unroll
            for (int kk = 0; kk < 4; ++kk) {
                short8 bfrag = *(const short8*)&stg[(n * 16 + lm) * 168 + kk * 32 + lg * 8];
                acc = __builtin_amdgcn_mfma_f32_16x16x32_bf16(qf[kk], bfrag, acc, 0, 0, 0);
            }
            #pragma unroll
            for (int e = 0; e < 4; ++e)
                o[(size_t)(t0 + m0 + lg * 4 + e) * VD + h * DV_ + qq * 64 + n * 16 + lm] = acc[e];
        }
        __syncthreads();
    }
}

// ---------------------------------------------------------------------------
// normgate: obf = bf16( RMSNorm(o)*gnw * swish(g) ).  One wave per row.
// ---------------------------------------------------------------------------
__global__ __launch_bounds__(256)
void normgate_kernel(const float* __restrict__ o, const ushort_t* __restrict__ gbf,
                     const float* __restrict__ gnw, ushort_t* __restrict__ obf) {
    const int t = threadIdx.x;
    const int w = t >> 6, lane = t & 63;
    const int row = blockIdx.x * 4 + w;
    const size_t base = (size_t)row * DV_ + lane * 4;

    float4 ov = *(const float4*)&o[base];
    float ssq = ov.x * ov.x + ov.y * ov.y + ov.z * ov.z + ov.w * ov.w;
    #pragma unroll
    for (int off = 32; off > 0; off >>= 1) ssq += __shfl_xor(ssq, off);
    const float rms = rsqrtf(ssq * (1.0f / DV_) + 1e-5f);

    uint2 gv2 = *(const uint2*)&gbf[base];
    float g0, g1, g2, g3;
    unpack2(gv2.x, g0, g1); unpack2(gv2.y, g2, g3);
    float4 wv = *(const float4*)&gnw[lane * 4];
    float o0 = ov.x * rms * wv.x * (g0 / (1.f + expf(-g0)));
    float o1 = ov.y * rms * wv.y * (g1 / (1.f + expf(-g1)));
    float o2 = ov.z * rms * wv.z * (g2 / (1.f + expf(-g2)));
    float o3 = ov.w * rms * wv.w * (g3 / (1.f + expf(-g3)));
    uint2 p;
    p.x = (u32)f2b(o0) | ((u32)f2b(o1) << 16);
    p.y = (u32)f2b(o2) | ((u32)f2b(o3) << 16);
    *(uint2*)&obf[base] = p;
}

// ---------------------------------------------------------------------------
extern "C" void kernel_launch(void* const* d_in, const int* in_sizes, int n_in,
                              void* d_out, int out_size, void* d_ws, size_t ws_size,
                              hipStream_t stream) {
    const float* x    = (const float*)d_in[0];
    const float* Wq   = (const float*)d_in[1];
    const float* Wk   = (const float*)d_in[2];
    const float* Wv   = (const float*)d_in[3];
    const float* Wg   = (const float*)d_in[4];
    const float* Wgk1 = (const float*)d_in[5];
    const float* Wgk2 = (const float*)d_in[6];
    const float* bgk2 = (const float*)d_in[7];
    const float* Wo   = (const float*)d_in[8];
    const float* gnw  = (const float*)d_in[9];

    float* ws = (float*)d_ws;
    // ---- workspace plan (float offsets), total 143.4 MB ----
    float* q      = ws;                           // BT*KD f32 ; later o (w/ kf)
    float* kf     = ws + 4194304;                 // BT*KD f32
    float* gk     = ws + 8388608;                 // BT*KD f32 ; later gbf
    ushort_t* vT  = (ushort_t*)(ws + 12582912);   // 8.39M u16
    ushort_t* Sst = (ushort_t*)(ws + 16777216);   // 16.78M u16 (33.55MB)
    ushort_t* vbf = (ushort_t*)(ws + 16777216);   // Sst 1st half (pre-chunk_state)
    ushort_t* wbf = (ushort_t*)(ws + 20971520);   // Sst 2nd half (transient W^T)
    ushort_t* gbf = (ushort_t*)(ws + 8388608);    // gk region (post-gateprep)
    ushort_t* obf = (ushort_t*)(ws + 16777216);   // Sst 1st half (post-fused)
    float* o      = ws;                           // overlays q+kf (post-gateprep)
    ushort_t* xbf = (ushort_t*)(ws + 25165824);   // BT*DM bf16
    ushort_t* qgb = (ushort_t*)(ws + 29360128);   // 4.19M u16
    ushort_t* kib = (ushort_t*)(ws + 31457280);
    ushort_t* kgb = (ushort_t*)(ws + 33554432);
    float* tmp16  = ws + 35651584;                // BT*16
    float* glast  = ws + 35782656;                // 65536 f32

    cvtx<<<4096, 256, 0, stream>>>(x, xbf, BT * DM);

    tcvt<<<dim3(32, 16), 256, 0, stream>>>(Wq, wbf, DM, KD);
    gemm_bf16<0><<<dim3(64, 4), 256, 0, stream>>>(xbf, wbf, q, BT, KD, DM);
    tcvt<<<dim3(32, 16), 256, 0, stream>>>(Wk, wbf, DM, KD);
    gemm_bf16<0><<<dim3(64, 4), 256, 0, stream>>>(xbf, wbf, kf, BT, KD, DM);
    tcvt<<<dim3(32, 32), 256, 0, stream>>>(Wv, wbf, DM, VD);
    gemm_bf16<1><<<dim3(64, 8), 256, 0, stream>>>(xbf, wbf, vbf, BT, VD, DM);

    lowrank_kernel<<<512, 256, 0, stream>>>(x, Wgk1, tmp16);
    gatek_kernel<<<16384, 256, 0, stream>>>(tmp16, Wgk2, bgk2, gk);
    gateprep_kernel<<<512, 128, 0, stream>>>(q, kf, gk, qgb, kib, kgb, glast);

    vtrans_kernel<<<512, 256, 0, stream>>>(vbf, vT);

    tcvt<<<dim3(32, 32), 256, 0, stream>>>(Wg, wbf, DM, VD);
    gemm_bf16<1><<<dim3(64, 8), 256, 0, stream>>>(xbf, wbf, gbf, BT, VD, DM);

    chunk_state<<<512, 256, 0, stream>>>(kgb, vT, Sst);
    scan_combine<<<128, 256, 0, stream>>>(Sst, glast);
    fused_chunk<<<512, 256, 0, stream>>>(qgb, kib, vT, Sst, o);

    normgate_kernel<<<8192, 256, 0, stream>>>(o, gbf, gnw, obf);
    tcvt<<<dim3(32, 32), 256, 0, stream>>>(Wo, wbf, VD, DM);
    gemm_bf16<0><<<dim3(64, 8), 256, 0, stream>>>(obf, wbf, (float*)d_out, BT, DM, VD);
}

// Round 4
// 402.632 us; speedup vs baseline: 3.8236x; 1.0236x over previous
//
#include <hip/hip_runtime.h>
#include <hip/hip_bf16.h>
#include <stdint.h>

#define B_  4
#define T_  2048
#define DM  1024
#define H_  4
#define DK_ 128
#define DV_ 256
#define KD  512     // H_*DK_
#define VD  1024    // H_*DV_
#define NCH 32      // num chunks
#define CC  64      // chunk len
#define BT  8192    // B_*T_
#define SCALE 0.08838834764831845f   // 1/sqrt(128)
#define GNORM_INV 0.0625f            // 1/16

typedef __attribute__((ext_vector_type(8))) short short8;   // 8 bf16 (4 VGPRs)
typedef __attribute__((ext_vector_type(4))) float f32x4;
typedef uint32_t u32;
typedef unsigned short ushort_t;

__device__ inline ushort_t f2b(float f) {               // f32 -> bf16 RNE
    u32 u = __builtin_bit_cast(u32, f);
    u32 r = (u + 0x7fffu + ((u >> 16) & 1u)) >> 16;
    return (ushort_t)r;
}
__device__ inline void unpack2(u32 u, float& lo, float& hi) {
    lo = __builtin_bit_cast(float, u << 16);
    hi = __builtin_bit_cast(float, u & 0xffff0000u);
}
// async global->LDS, 16B per lane; LDS dest is wave-uniform base + lane*16
__device__ inline void gload_lds16(const void* g, void* l) {
    __builtin_amdgcn_global_load_lds(
        (const __attribute__((address_space(1))) uint32_t*)g,
        (__attribute__((address_space(3))) uint32_t*)l, 16, 0, 0);
}

// ---------------------------------------------------------------------------
// cvtx: f32 -> bf16 straight conversion (8 elems/thread)
// ---------------------------------------------------------------------------
__global__ __launch_bounds__(256)
void cvtx(const float* __restrict__ x, ushort_t* __restrict__ xb, int n) {
    int idx = (blockIdx.x * 256 + threadIdx.x) * 8;
    if (idx >= n) return;
    float4 a = *(const float4*)&x[idx];
    float4 b = *(const float4*)&x[idx + 4];
    uint4 p;
    p.x = (u32)f2b(a.x) | ((u32)f2b(a.y) << 16);
    p.y = (u32)f2b(a.z) | ((u32)f2b(a.w) << 16);
    p.z = (u32)f2b(b.x) | ((u32)f2b(b.y) << 16);
    p.w = (u32)f2b(b.z) | ((u32)f2b(b.w) << 16);
    *(uint4*)&xb[idx] = p;
}

// ---------------------------------------------------------------------------
// tcvt: W[K][N] f32 -> Wt[N][K] bf16 (transpose + convert), 32x32 LDS tiles
// ---------------------------------------------------------------------------
__global__ __launch_bounds__(256)
void tcvt(const float* __restrict__ W, ushort_t* __restrict__ Wt, int K, int N) {
    __shared__ float tile[32][33];
    const int k0 = blockIdx.x * 32, n0 = blockIdx.y * 32;
    const int r = threadIdx.x >> 3, c4 = (threadIdx.x & 7) * 4;
    float4 wv = *(const float4*)&W[(size_t)(k0 + r) * N + n0 + c4];
    tile[r][c4 + 0] = wv.x; tile[r][c4 + 1] = wv.y;
    tile[r][c4 + 2] = wv.z; tile[r][c4 + 3] = wv.w;
    __syncthreads();
    u32 lo = (u32)f2b(tile[c4 + 0][r]) | ((u32)f2b(tile[c4 + 1][r]) << 16);
    u32 hi = (u32)f2b(tile[c4 + 2][r]) | ((u32)f2b(tile[c4 + 3][r]) << 16);
    uint2 o2; o2.x = lo; o2.y = hi;
    *(uint2*)&Wt[(size_t)(n0 + r) * K + k0 + c4] = o2;
}

// ---------------------------------------------------------------------------
// bf16 MFMA GEMM: C[M,N] = A[M,K] @ Wt[N,K]^T.  128x128 tile, BK=32, 4 waves,
// global_load_lds(16B) staging into linear LDS [128][32] (m97 structure).
// ---------------------------------------------------------------------------
template<int OUTBF>
__global__ __launch_bounds__(256)
void gemm_bf16(const ushort_t* __restrict__ A, const ushort_t* __restrict__ Bt,
               void* __restrict__ Cout, int M, int N, int K) {
    __shared__ ushort_t Al[128 * 32];   // 8 KB, linear (gload_lds dest)
    __shared__ ushort_t Bl[128 * 32];
    const int t = threadIdx.x;
    const int wave = t >> 6, lane = t & 63;
    const int wr = wave >> 1, wc = wave & 1;
    const int row0 = blockIdx.x * 128, col0 = blockIdx.y * 128;
    const int lm = lane & 15, lk = (lane >> 4) * 8;

    // staging decomposition: issue i covers LDS bytes [i*4096 + t*16)
    const int b0 = t * 16;                 // issue-0 byte for this thread
    const int r0 = b0 >> 6, c0 = (b0 & 63) >> 1;          // tile row / elem col
    const int r1 = (4096 + b0) >> 6, c1 = ((4096 + b0) & 63) >> 1;
    ushort_t* ldsA0 = &Al[(wave * 1024) >> 1];
    ushort_t* ldsA1 = &Al[(4096 + wave * 1024) >> 1];
    ushort_t* ldsB0 = &Bl[(wave * 1024) >> 1];
    ushort_t* ldsB1 = &Bl[(4096 + wave * 1024) >> 1];

    f32x4 acc[4][4];
    #pragma unroll
    for (int i = 0; i < 4; ++i)
        #pragma unroll
        for (int j = 0; j < 4; ++j) acc[i][j] = f32x4{0.f, 0.f, 0.f, 0.f};

    const ushort_t* Ap = A + (size_t)row0 * K;
    const ushort_t* Bp = Bt + (size_t)col0 * K;

    for (int k0 = 0; k0 < K; k0 += 32) {
        __syncthreads();
        gload_lds16(Ap + (size_t)r0 * K + k0 + c0, ldsA0);
        gload_lds16(Ap + (size_t)r1 * K + k0 + c1, ldsA1);
        gload_lds16(Bp + (size_t)r0 * K + k0 + c0, ldsB0);
        gload_lds16(Bp + (size_t)r1 * K + k0 + c1, ldsB1);
        __syncthreads();                       // drains vmcnt -> LDS ready
        short8 af[4], bfr[4];
        #pragma unroll
        for (int f = 0; f < 4; ++f)
            af[f] = *(const short8*)(&Al[(wr * 64 + f * 16 + lm) * 32 + lk]);
        #pragma unroll
        for (int f = 0; f < 4; ++f)
            bfr[f] = *(const short8*)(&Bl[(wc * 64 + f * 16 + lm) * 32 + lk]);
        #pragma unroll
        for (int i = 0; i < 4; ++i)
            #pragma unroll
            for (int j = 0; j < 4; ++j)
                acc[i][j] = __builtin_amdgcn_mfma_f32_16x16x32_bf16(af[i], bfr[j], acc[i][j], 0, 0, 0);
    }
    const int orow = row0 + wr * 64 + (lane >> 4) * 4;
    const int ocol = col0 + wc * 64 + lm;
    #pragma unroll
    for (int i = 0; i < 4; ++i)
        #pragma unroll
        for (int j = 0; j < 4; ++j)
            #pragma unroll
            for (int e = 0; e < 4; ++e) {
                int rr = orow + i * 16 + e, cc = ocol + j * 16;
                if (OUTBF) ((ushort_t*)Cout)[(size_t)rr * N + cc] = f2b(acc[i][j][e]);
                else       ((float*)Cout)[(size_t)rr * N + cc]   = acc[i][j][e];
            }
}

// ---------------------------------------------------------------------------
// Low-rank gate stage 1: tmp[BT,16] = x @ Wgk1.  One block per row:
// 256 thr = 16 k-segments x 16 cols, LDS tree-reduce (no long dep chains).
// ---------------------------------------------------------------------------
__global__ __launch_bounds__(256)
void lowrank_kernel(const float* __restrict__ x, const float* __restrict__ W1,
                    float* __restrict__ tmp) {
    __shared__ float part[16][20];
    const int row = blockIdx.x;
    const int t = threadIdx.x;
    const int ks = t >> 4, c = t & 15;
    const float* xp = x + (size_t)row * DM + ks * 64;
    const float* wp0 = W1 + (size_t)(ks * 64) * 16 + c;
    float acc = 0.f;
    #pragma unroll
    for (int i = 0; i < 16; ++i) {
        float4 xv = *(const float4*)&xp[i * 4];
        const float* wp = wp0 + i * 64;
        acc += xv.x * wp[0] + xv.y * wp[16] + xv.z * wp[32] + xv.w * wp[48];
    }
    part[ks][c] = acc;
    __syncthreads();
    if (t < 16) {
        float s = 0.f;
        #pragma unroll
        for (int i = 0; i < 16; ++i) s += part[i][t];
        tmp[row * 16 + t] = s;
    }
}

// ---------------------------------------------------------------------------
// Gate stage 2: gk[BT,512] = log_sigmoid(tmp @ Wgk2 + b) / 16
// ---------------------------------------------------------------------------
__global__ __launch_bounds__(256)
void gatek_kernel(const float* __restrict__ tmp, const float* __restrict__ W2,
                  const float* __restrict__ bias, float* __restrict__ gk) {
    const int idx = blockIdx.x * 256 + threadIdx.x;
    const int bt = idx >> 9, c = idx & 511;
    float z = bias[c];
    #pragma unroll
    for (int j = 0; j < 16; ++j)
        z += tmp[bt * 16 + j] * W2[j * KD + c];
    float ls = fminf(z, 0.f) - log1pf(expf(-fabsf(z)));
    gk[idx] = ls * GNORM_INV;
}

// ---------------------------------------------------------------------------
// gateprep: q,k,gk (f32, [bt][KD]) -> qgb,kib,kgb (bf16, per-chunk [64][128])
// ---------------------------------------------------------------------------
__global__ __launch_bounds__(128)
void gateprep_kernel(const float* __restrict__ q, const float* __restrict__ kf,
                     const float* __restrict__ gk,
                     ushort_t* __restrict__ qgb, ushort_t* __restrict__ kib,
                     ushort_t* __restrict__ kgb, float* __restrict__ glast) {
    const int bid = blockIdx.x;
    const int c = bid & 31, bh = bid >> 5;
    const int b = bh >> 2, h = bh & 3;
    const int d = threadIdx.x;
    const int t0 = b * T_ + c * CC;
    const int gbase = t0 * KD + h * DK_ + d;
    const int obase = bid * (CC * DK_) + d;

    float total = 0.f;
    for (int i = 0; i < CC; ++i) total += gk[gbase + i * KD];

    float G = 0.f;
    for (int i = 0; i < CC; ++i) {
        const int gi = gbase + i * KD;
        G += gk[gi];
        float qv = q[gi], kv = kf[gi];
        qgb[obase + i * DK_] = f2b(qv * expf(G) * SCALE);
        kib[obase + i * DK_] = f2b(kv * expf(-G));
        kgb[obase + i * DK_] = f2b(kv * expf(total - G));
    }
    glast[bid * DK_ + d] = expf(total);
}

// ---------------------------------------------------------------------------
// vtrans: vbf [bt][VD] -> vT per-chunk [dv=256][j=64].  block=(bh,c)
// ---------------------------------------------------------------------------
__global__ __launch_bounds__(256)
void vtrans_kernel(const ushort_t* __restrict__ vbf, ushort_t* __restrict__ vT) {
    __shared__ ushort_t vl[64][264];
    const int bid = blockIdx.x;
    const int c = bid & 31, bh = bid >> 5;
    const int b = bh >> 2, h = bh & 3;
    const int t0 = b * T_ + c * CC;
    const int t = threadIdx.x;

    #pragma unroll
    for (int m = 0; m < 8; ++m) {
        int p = t + m * 256;
        int j = p >> 5, d8 = (p & 31) * 8;
        *(uint4*)&vl[j][d8] = *(const uint4*)&vbf[(size_t)(t0 + j) * VD + h * DV_ + d8];
    }
    __syncthreads();

    const size_t outb = (size_t)bid * (256 * 64);
    #pragma unroll
    for (int it = 0; it < 2; ++it) {
        int dv = it * 128 + (t >> 1);
        int j0 = (t & 1) * 32;
        u32 vv[16];
        #pragma unroll
        for (int wi = 0; wi < 16; ++wi)
            vv[wi] = (u32)vl[j0 + 2 * wi][dv] | ((u32)vl[j0 + 2 * wi + 1][dv] << 16);
        ushort_t* dst = &vT[outb + (size_t)dv * 64 + j0];
        *(uint4*)(dst + 0)  = make_uint4(vv[0], vv[1], vv[2], vv[3]);
        *(uint4*)(dst + 8)  = make_uint4(vv[4], vv[5], vv[6], vv[7]);
        *(uint4*)(dst + 16) = make_uint4(vv[8], vv[9], vv[10], vv[11]);
        *(uint4*)(dst + 24) = make_uint4(vv[12], vv[13], vv[14], vv[15]);
    }
}

// ---------------------------------------------------------------------------
// chunk_state (MFMA): Sst^T[dv=256][dk=128] = vT(256x64) @ kg(64x128)
// ---------------------------------------------------------------------------
__global__ __launch_bounds__(256)
void chunk_state(const ushort_t* __restrict__ kgb, const ushort_t* __restrict__ vT,
                 ushort_t* __restrict__ Sst) {
    __shared__ ushort_t kgT[128 * 72];
    const int bid = blockIdx.x;
    const int t = threadIdx.x;
    const size_t kgbase = (size_t)bid * (CC * DK_);
    const size_t vtbase = (size_t)bid * (256 * 64);
    const size_t sbase  = (size_t)bid * (256 * 128);

    #pragma unroll
    for (int m = 0; m < 4; ++m) {
        int p = t + m * 256;
        int j = p >> 4, d0 = (p & 15) * 8;
        uint4 r = *(const uint4*)&kgb[kgbase + (size_t)j * DK_ + d0];
        kgT[(d0 + 0) * 72 + j] = (ushort_t)(r.x & 0xffff);
        kgT[(d0 + 1) * 72 + j] = (ushort_t)(r.x >> 16);
        kgT[(d0 + 2) * 72 + j] = (ushort_t)(r.y & 0xffff);
        kgT[(d0 + 3) * 72 + j] = (ushort_t)(r.y >> 16);
        kgT[(d0 + 4) * 72 + j] = (ushort_t)(r.z & 0xffff);
        kgT[(d0 + 5) * 72 + j] = (ushort_t)(r.z >> 16);
        kgT[(d0 + 6) * 72 + j] = (ushort_t)(r.w & 0xffff);
        kgT[(d0 + 7) * 72 + j] = (ushort_t)(r.w >> 16);
    }
    __syncthreads();

    const int w = t >> 6, lane = t & 63;
    const int lm = lane & 15, lg = lane >> 4;
    #pragma unroll
    for (int mm = 0; mm < 4; ++mm) {
        const int mt = w * 4 + mm;
        short8 a0 = *(const short8*)&vT[vtbase + (size_t)(mt * 16 + lm) * 64 + lg * 8];
        short8 a1 = *(const short8*)&vT[vtbase + (size_t)(mt * 16 + lm) * 64 + 32 + lg * 8];
        #pragma unroll
        for (int n = 0; n < 8; ++n) {
            f32x4 acc = {0.f, 0.f, 0.f, 0.f};
            short8 b0 = *(const short8*)&kgT[(n * 16 + lm) * 72 + lg * 8];
            short8 b1 = *(const short8*)&kgT[(n * 16 + lm) * 72 + 32 + lg * 8];
            acc = __builtin_amdgcn_mfma_f32_16x16x32_bf16(a0, b0, acc, 0, 0, 0);
            acc = __builtin_amdgcn_mfma_f32_16x16x32_bf16(a1, b1, acc, 0, 0, 0);
            #pragma unroll
            for (int e = 0; e < 4; ++e)
                Sst[sbase + (size_t)(mt * 16 + lg * 4 + e) * 128 + n * 16 + lm] = f2b(acc[e]);
        }
    }
}

// ---------------------------------------------------------------------------
// scan_combine: in-place M_c -> exclusive prefix P_c. 256 blocks (bh, dv/16).
// ---------------------------------------------------------------------------
__global__ __launch_bounds__(256)
void scan_combine(ushort_t* __restrict__ Sst, const float* __restrict__ glast) {
    const int bid = blockIdx.x;
    const int dvt = bid & 15, bh = bid >> 4;
    const int t = threadIdx.x;
    const int dv = dvt * 16 + (t >> 4);
    const int dk0 = (t & 15) * 8;

    float P[8];
    #pragma unroll
    for (int e = 0; e < 8; ++e) P[e] = 0.f;

    for (int c = 0; c < NCH; ++c) {
        const size_t base = ((size_t)(bh * NCH + c) * 256 + dv) * 128 + dk0;
        uint4 m0 = *(const uint4*)&Sst[base];
        u32 wd[4];
        #pragma unroll
        for (int e = 0; e < 4; ++e)
            wd[e] = (u32)f2b(P[2 * e]) | ((u32)f2b(P[2 * e + 1]) << 16);
        *(uint4*)&Sst[base] = make_uint4(wd[0], wd[1], wd[2], wd[3]);
        float mv[8];
        unpack2(m0.x, mv[0], mv[1]); unpack2(m0.y, mv[2], mv[3]);
        unpack2(m0.z, mv[4], mv[5]); unpack2(m0.w, mv[6], mv[7]);
        const float* glp = &glast[(size_t)(bh * NCH + c) * DK_ + dk0];
        float4 g0 = *(const float4*)&glp[0];
        float4 g1 = *(const float4*)&glp[4];
        float gl[8] = {g0.x, g0.y, g0.z, g0.w, g1.x, g1.y, g1.z, g1.w};
        #pragma unroll
        for (int e = 0; e < 8; ++e) P[e] = gl[e] * P[e] + mv[e];
    }
}

// ---------------------------------------------------------------------------
// fused_chunk (MFMA): o = tril(qg@ki^T)@v + qg@P per chunk; bf16 out.
// ---------------------------------------------------------------------------
__global__ __launch_bounds__(256)
void fused_chunk(const ushort_t* __restrict__ qgb, const ushort_t* __restrict__ kib,
                 const ushort_t* __restrict__ vT, const ushort_t* __restrict__ Sst,
                 ushort_t* __restrict__ ob) {
    __shared__ __align__(16) ushort_t lds[24064];   // 48.1KB
    ushort_t* stg = lds;                 // [64][168]
    ushort_t* vq  = lds + 10752;         // [64][104]
    ushort_t* Al  = lds + 17408;         // [64][104]

    const int bid = blockIdx.x;
    const int c = bid & 31, bh = bid >> 5;
    const int b = bh >> 2, h = bh & 3;
    const int t0 = b * T_ + c * CC;
    const int t = threadIdx.x;
    const int w = t >> 6, lane = t & 63;
    const int lm = lane & 15, lg = lane >> 4;
    const int m0 = w * 16;

    const size_t qbase  = (size_t)bid * (CC * DK_);
    const size_t vtbase = (size_t)bid * (256 * 64);
    const size_t sbase  = (size_t)bid * (256 * 128);

    short8 qf[4];
    #pragma unroll
    for (int kk = 0; kk < 4; ++kk)
        qf[kk] = *(const short8*)&qgb[qbase + (size_t)(m0 + lm) * DK_ + kk * 32 + lg * 8];

    #pragma unroll
    for (int m = 0; m < 4; ++m) {
        int p = t + m * 256;
        int j = p >> 4, d0 = (p & 15) * 8;
        *(uint4*)&stg[j * 168 + d0] = *(const uint4*)&kib[qbase + (size_t)j * DK_ + d0];
    }
    __syncthreads();

    f32x4 accA[4];
    #pragma unroll
    for (int jt = 0; jt < 4; ++jt) accA[jt] = f32x4{0.f, 0.f, 0.f, 0.f};
    #pragma unroll
    for (int jt = 0; jt < 4; ++jt)
        #pragma unroll
        for (int kk = 0; kk < 4; ++kk) {
            short8 bfrag = *(const short8*)&stg[(jt * 16 + lm) * 168 + kk * 32 + lg * 8];
            accA[jt] = __builtin_amdgcn_mfma_f32_16x16x32_bf16(qf[kk], bfrag, accA[jt], 0, 0, 0);
        }
    #pragma unroll
    for (int jt = 0; jt < 4; ++jt)
        #pragma unroll
        for (int e = 0; e < 4; ++e) {
            int i = m0 + lg * 4 + e, j = jt * 16 + lm;
            Al[i * 104 + j] = f2b(j <= i ? accA[jt][e] : 0.f);
        }
    __syncthreads();

    short8 af[2];
    #pragma unroll
    for (int kk = 0; kk < 2; ++kk)
        af[kk] = *(const short8*)&Al[(m0 + lm) * 104 + kk * 32 + lg * 8];

    #pragma unroll 1
    for (int qq = 0; qq < 4; ++qq) {
        #pragma unroll
        for (int m = 0; m < 2; ++m) {
            int p = t + m * 256;
            int dvr = p >> 3, d0 = (p & 7) * 8;
            *(uint4*)&vq[dvr * 104 + d0] =
                *(const uint4*)&vT[vtbase + (size_t)(qq * 64 + dvr) * 64 + d0];
        }
        #pragma unroll
        for (int m = 0; m < 4; ++m) {
            int p = t + m * 256;
            int dvr = p >> 4, d0 = (p & 15) * 8;
            *(uint4*)&stg[dvr * 168 + d0] =
                *(const uint4*)&Sst[sbase + (size_t)(qq * 64 + dvr) * 128 + d0];
        }
        __syncthreads();
        #pragma unroll
        for (int n = 0; n < 4; ++n) {
            f32x4 acc = {0.f, 0.f, 0.f, 0.f};
            #pragma unroll
            for (int kk = 0; kk < 2; ++kk) {
                short8 bfrag = *(const short8*)&vq[(n * 16 + lm) * 104 + kk * 32 + lg * 8];
                acc = __builtin_amdgcn_mfma_f32_16x16x32_bf16(af[kk], bfrag, acc, 0, 0, 0);
            }
            #pragma unroll
            for (int kk = 0; kk < 4; ++kk) {
                short8 bfrag = *(const short8*)&stg[(n * 16 + lm) * 168 + kk * 32 + lg * 8];
                acc = __builtin_amdgcn_mfma_f32_16x16x32_bf16(qf[kk], bfrag, acc, 0, 0, 0);
            }
            #pragma unroll
            for (int e = 0; e < 4; ++e)
                ob[(size_t)(t0 + m0 + lg * 4 + e) * VD + h * DV_ + qq * 64 + n * 16 + lm] = f2b(acc[e]);
        }
        __syncthreads();
    }
}

// ---------------------------------------------------------------------------
// normgate: obf = bf16( RMSNorm(o)*gnw * swish(g) ), o in bf16 now.
// ---------------------------------------------------------------------------
__global__ __launch_bounds__(256)
void normgate_kernel(const ushort_t* __restrict__ ob, const ushort_t* __restrict__ gbf,
                     const float* __restrict__ gnw, ushort_t* __restrict__ obf) {
    const int t = threadIdx.x;
    const int w = t >> 6, lane = t & 63;
    const int row = blockIdx.x * 4 + w;
    const size_t base = (size_t)row * DV_ + lane * 4;

    uint2 ov2 = *(const uint2*)&ob[base];
    float o0v, o1v, o2v, o3v;
    unpack2(ov2.x, o0v, o1v); unpack2(ov2.y, o2v, o3v);
    float ssq = o0v * o0v + o1v * o1v + o2v * o2v + o3v * o3v;
    #pragma unroll
    for (int off = 32; off > 0; off >>= 1) ssq += __shfl_xor(ssq, off);
    const float rms = rsqrtf(ssq * (1.0f / DV_) + 1e-5f);

    uint2 gv2 = *(const uint2*)&gbf[base];
    float g0, g1, g2, g3;
    unpack2(gv2.x, g0, g1); unpack2(gv2.y, g2, g3);
    float4 wv = *(const float4*)&gnw[lane * 4];
    float r0 = o0v * rms * wv.x * (g0 / (1.f + expf(-g0)));
    float r1 = o1v * rms * wv.y * (g1 / (1.f + expf(-g1)));
    float r2 = o2v * rms * wv.z * (g2 / (1.f + expf(-g2)));
    float r3 = o3v * rms * wv.w * (g3 / (1.f + expf(-g3)));
    uint2 p;
    p.x = (u32)f2b(r0) | ((u32)f2b(r1) << 16);
    p.y = (u32)f2b(r2) | ((u32)f2b(r3) << 16);
    *(uint2*)&obf[base] = p;
}

// ---------------------------------------------------------------------------
extern "C" void kernel_launch(void* const* d_in, const int* in_sizes, int n_in,
                              void* d_out, int out_size, void* d_ws, size_t ws_size,
                              hipStream_t stream) {
    const float* x    = (const float*)d_in[0];
    const float* Wq   = (const float*)d_in[1];
    const float* Wk   = (const float*)d_in[2];
    const float* Wv   = (const float*)d_in[3];
    const float* Wg   = (const float*)d_in[4];
    const float* Wgk1 = (const float*)d_in[5];
    const float* Wgk2 = (const float*)d_in[6];
    const float* bgk2 = (const float*)d_in[7];
    const float* Wo   = (const float*)d_in[8];
    const float* gnw  = (const float*)d_in[9];

    float* ws = (float*)d_ws;
    float* q      = ws;                           // BT*KD f32 ; later ob (bf16)
    float* kf     = ws + 4194304;                 // BT*KD f32
    float* gk     = ws + 8388608;                 // BT*KD f32 ; later gbf
    ushort_t* vT  = (ushort_t*)(ws + 12582912);   // 8.39M u16
    ushort_t* Sst = (ushort_t*)(ws + 16777216);   // 16.78M u16
    ushort_t* vbf = (ushort_t*)(ws + 16777216);   // Sst 1st half (pre-chunk_state)
    ushort_t* wbf = (ushort_t*)(ws + 20971520);   // Sst 2nd half (transient W^T)
    ushort_t* gbf = (ushort_t*)(ws + 8388608);    // gk region (post-gateprep)
    ushort_t* obf = (ushort_t*)(ws + 16777216);   // Sst 1st half (post-fused)
    ushort_t* ob  = (ushort_t*)ws;                // bf16 o, overlays q (post-gateprep)
    ushort_t* xbf = (ushort_t*)(ws + 25165824);   // BT*DM bf16
    ushort_t* qgb = (ushort_t*)(ws + 29360128);
    ushort_t* kib = (ushort_t*)(ws + 31457280);
    ushort_t* kgb = (ushort_t*)(ws + 33554432);
    float* tmp16  = ws + 35651584;
    float* glast  = ws + 35782656;

    cvtx<<<4096, 256, 0, stream>>>(x, xbf, BT * DM);

    tcvt<<<dim3(32, 16), 256, 0, stream>>>(Wq, wbf, DM, KD);
    gemm_bf16<0><<<dim3(64, 4), 256, 0, stream>>>(xbf, wbf, q, BT, KD, DM);
    tcvt<<<dim3(32, 16), 256, 0, stream>>>(Wk, wbf, DM, KD);
    gemm_bf16<0><<<dim3(64, 4), 256, 0, stream>>>(xbf, wbf, kf, BT, KD, DM);
    tcvt<<<dim3(32, 32), 256, 0, stream>>>(Wv, wbf, DM, VD);
    gemm_bf16<1><<<dim3(64, 8), 256, 0, stream>>>(xbf, wbf, vbf, BT, VD, DM);

    lowrank_kernel<<<8192, 256, 0, stream>>>(x, Wgk1, tmp16);
    gatek_kernel<<<16384, 256, 0, stream>>>(tmp16, Wgk2, bgk2, gk);
    gateprep_kernel<<<512, 128, 0, stream>>>(q, kf, gk, qgb, kib, kgb, glast);

    vtrans_kernel<<<512, 256, 0, stream>>>(vbf, vT);

    tcvt<<<dim3(32, 32), 256, 0, stream>>>(Wg, wbf, DM, VD);
    gemm_bf16<1><<<dim3(64, 8), 256, 0, stream>>>(xbf, wbf, gbf, BT, VD, DM);

    chunk_state<<<512, 256, 0, stream>>>(kgb, vT, Sst);
    scan_combine<<<256, 256, 0, stream>>>(Sst, glast);
    fused_chunk<<<512, 256, 0, stream>>>(qgb, kib, vT, Sst, ob);

    normgate_kernel<<<8192, 256, 0, stream>>>(ob, gbf, gnw, obf);
    tcvt<<<dim3(32, 32), 256, 0, stream>>>(Wo, wbf, VD, DM);
    gemm_bf16<0><<<dim3(64, 8), 256, 0, stream>>>(obf, wbf, (float*)d_out, BT, DM, VD);
}

// Round 8
// 360.091 us; speedup vs baseline: 4.2753x; 1.1181x over previous
//
#include <hip/hip_runtime.h>
#include <hip/hip_bf16.h>
#include <stdint.h>

#define B_  4
#define T_  2048
#define DM  1024
#define H_  4
#define DK_ 128
#define DV_ 256
#define KD  512     // H_*DK_
#define VD  1024    // H_*DV_
#define NCH 32      // num chunks
#define CC  64      // chunk len
#define BT  8192    // B_*T_
#define SCALE 0.08838834764831845f   // 1/sqrt(128)
#define GNORM_INV 0.0625f            // 1/16

typedef __attribute__((ext_vector_type(8))) short short8;   // 8 bf16 (4 VGPRs)
typedef __attribute__((ext_vector_type(4))) float f32x4;
typedef uint32_t u32;
typedef unsigned short ushort_t;

__device__ inline ushort_t f2b(float f) {               // f32 -> bf16 RNE
    u32 u = __builtin_bit_cast(u32, f);
    u32 r = (u + 0x7fffu + ((u >> 16) & 1u)) >> 16;
    return (ushort_t)r;
}
__device__ inline void unpack2(u32 u, float& lo, float& hi) {
    lo = __builtin_bit_cast(float, u << 16);
    hi = __builtin_bit_cast(float, u & 0xffff0000u);
}
// async global->LDS, 16B per lane; LDS dest is wave-uniform base + lane*16
__device__ inline void gload_lds16(const void* g, void* l) {
    __builtin_amdgcn_global_load_lds(
        (const __attribute__((address_space(1))) uint32_t*)g,
        (__attribute__((address_space(3))) uint32_t*)l, 16, 0, 0);
}

// ---------------------------------------------------------------------------
// cvtx: f32 -> bf16 (8 elems/thread)
// ---------------------------------------------------------------------------
__global__ __launch_bounds__(256)
void cvtx(const float* __restrict__ x, ushort_t* __restrict__ xb, int n) {
    int idx = (blockIdx.x * 256 + threadIdx.x) * 8;
    if (idx >= n) return;
    float4 a = *(const float4*)&x[idx];
    float4 b = *(const float4*)&x[idx + 4];
    uint4 p;
    p.x = (u32)f2b(a.x) | ((u32)f2b(a.y) << 16);
    p.y = (u32)f2b(a.z) | ((u32)f2b(a.w) << 16);
    p.z = (u32)f2b(b.x) | ((u32)f2b(b.y) << 16);
    p.w = (u32)f2b(b.z) | ((u32)f2b(b.w) << 16);
    *(uint4*)&xb[idx] = p;
}

// ---------------------------------------------------------------------------
// tcvt: W[K][N] f32 -> Wt[N][K] bf16 (transpose + convert), 32x32 LDS tiles
// ---------------------------------------------------------------------------
__global__ __launch_bounds__(256)
void tcvt(const float* __restrict__ W, ushort_t* __restrict__ Wt, int K, int N) {
    __shared__ float tile[32][33];
    const int k0 = blockIdx.x * 32, n0 = blockIdx.y * 32;
    const int r = threadIdx.x >> 3, c4 = (threadIdx.x & 7) * 4;
    float4 wv = *(const float4*)&W[(size_t)(k0 + r) * N + n0 + c4];
    tile[r][c4 + 0] = wv.x; tile[r][c4 + 1] = wv.y;
    tile[r][c4 + 2] = wv.z; tile[r][c4 + 3] = wv.w;
    __syncthreads();
    u32 lo = (u32)f2b(tile[c4 + 0][r]) | ((u32)f2b(tile[c4 + 1][r]) << 16);
    u32 hi = (u32)f2b(tile[c4 + 2][r]) | ((u32)f2b(tile[c4 + 3][r]) << 16);
    uint2 o2; o2.x = lo; o2.y = hi;
    *(uint2*)&Wt[(size_t)(n0 + r) * K + k0 + c4] = o2;
}

// ---------------------------------------------------------------------------
// w1trans: W1[1024][16] f32 -> w1t[16][1024] bf16
// ---------------------------------------------------------------------------
__global__ __launch_bounds__(256)
void w1trans(const float* __restrict__ W1, ushort_t* __restrict__ w1t) {
    int idx = blockIdx.x * 256 + threadIdx.x;   // 16384
    int k = idx >> 4, n = idx & 15;
    w1t[n * 1024 + k] = f2b(W1[k * 16 + n]);
}

// ---------------------------------------------------------------------------
// gemm_qkv: fused q/k/v projection. A=xbf[8192][1024], Wt=wcat[2048][1024].
// 128x128 tiles, 1D grid 1024 (64x16), XCD swizzle. Outputs:
//   col tiles 0-3 -> q (f32, N=512), 4-7 -> kf (f32), 8-15 -> vbf (bf16, N=1024)
// ---------------------------------------------------------------------------
__global__ __launch_bounds__(256)
void gemm_qkv(const ushort_t* __restrict__ A, const ushort_t* __restrict__ Bt,
              float* __restrict__ qo, float* __restrict__ ko,
              ushort_t* __restrict__ vo) {
    __shared__ ushort_t Al[128 * 32];
    __shared__ ushort_t Bl[128 * 32];
    const int wg = blockIdx.x;
    const int swz = (wg & 7) * 128 + (wg >> 3);   // 1024 = 8*128, bijective
    const int bx = swz & 63, by = swz >> 6;       // 64 x 16
    const int t = threadIdx.x;
    const int wave = t >> 6, lane = t & 63;
    const int wr = wave >> 1, wc = wave & 1;
    const int row0 = bx * 128, col0 = by * 128;
    const int lm = lane & 15, lk = (lane >> 4) * 8;

    const int b0 = t * 16;
    const int r0 = b0 >> 6, c0 = (b0 & 63) >> 1;
    const int r1 = (4096 + b0) >> 6, c1 = ((4096 + b0) & 63) >> 1;
    ushort_t* ldsA0 = &Al[(wave * 1024) >> 1];
    ushort_t* ldsA1 = &Al[(4096 + wave * 1024) >> 1];
    ushort_t* ldsB0 = &Bl[(wave * 1024) >> 1];
    ushort_t* ldsB1 = &Bl[(4096 + wave * 1024) >> 1];

    f32x4 acc[4][4];
    #pragma unroll
    for (int i = 0; i < 4; ++i)
        #pragma unroll
        for (int j = 0; j < 4; ++j) acc[i][j] = f32x4{0.f, 0.f, 0.f, 0.f};

    const ushort_t* Ap = A + (size_t)row0 * DM;
    const ushort_t* Bp = Bt + (size_t)col0 * DM;

    for (int k0 = 0; k0 < DM; k0 += 32) {
        __syncthreads();
        gload_lds16(Ap + (size_t)r0 * DM + k0 + c0, ldsA0);
        gload_lds16(Ap + (size_t)r1 * DM + k0 + c1, ldsA1);
        gload_lds16(Bp + (size_t)r0 * DM + k0 + c0, ldsB0);
        gload_lds16(Bp + (size_t)r1 * DM + k0 + c1, ldsB1);
        __syncthreads();
        short8 af[4], bfr[4];
        #pragma unroll
        for (int f = 0; f < 4; ++f)
            af[f] = *(const short8*)(&Al[(wr * 64 + f * 16 + lm) * 32 + lk]);
        #pragma unroll
        for (int f = 0; f < 4; ++f)
            bfr[f] = *(const short8*)(&Bl[(wc * 64 + f * 16 + lm) * 32 + lk]);
        #pragma unroll
        for (int i = 0; i < 4; ++i)
            #pragma unroll
            for (int j = 0; j < 4; ++j)
                acc[i][j] = __builtin_amdgcn_mfma_f32_16x16x32_bf16(af[i], bfr[j], acc[i][j], 0, 0, 0);
    }
    const int orow = row0 + wr * 64 + (lane >> 4) * 4;
    const int cbase = col0 + wc * 64 + lm;        // global col 0..2047
    if (by < 8) {
        float* C = (by < 4) ? qo : ko;
        const int cc0 = cbase - ((by < 4) ? 0 : 512);
        #pragma unroll
        for (int i = 0; i < 4; ++i)
            #pragma unroll
            for (int j = 0; j < 4; ++j)
                #pragma unroll
                for (int e = 0; e < 4; ++e)
                    C[(size_t)(orow + i * 16 + e) * KD + cc0 + j * 16] = acc[i][j][e];
    } else {
        const int cc0 = cbase - 1024;
        #pragma unroll
        for (int i = 0; i < 4; ++i)
            #pragma unroll
            for (int j = 0; j < 4; ++j)
                #pragma unroll
                for (int e = 0; e < 4; ++e)
                    vo[(size_t)(orow + i * 16 + e) * VD + cc0 + j * 16] = f2b(acc[i][j][e]);
    }
}

// ---------------------------------------------------------------------------
// gemm_bf16<OUTBF>: C[M,N] = A[M,K]bf16 @ Wt[N,K]^T.  1D swizzled grid.
// ---------------------------------------------------------------------------
template<int OUTBF>
__global__ __launch_bounds__(256)
void gemm_bf16(const ushort_t* __restrict__ A, const ushort_t* __restrict__ Bt,
               void* __restrict__ Cout, int M, int N, int K, int nbx) {
    __shared__ ushort_t Al[128 * 32];
    __shared__ ushort_t Bl[128 * 32];
    const int nwg = gridDim.x;
    const int cpx = nwg >> 3;
    const int wg = blockIdx.x;
    const int swz = (wg & 7) * cpx + (wg >> 3);
    const int bx = swz % nbx, by = swz / nbx;
    const int t = threadIdx.x;
    const int wave = t >> 6, lane = t & 63;
    const int wr = wave >> 1, wc = wave & 1;
    const int row0 = bx * 128, col0 = by * 128;
    const int lm = lane & 15, lk = (lane >> 4) * 8;

    const int b0 = t * 16;
    const int r0 = b0 >> 6, c0 = (b0 & 63) >> 1;
    const int r1 = (4096 + b0) >> 6, c1 = ((4096 + b0) & 63) >> 1;
    ushort_t* ldsA0 = &Al[(wave * 1024) >> 1];
    ushort_t* ldsA1 = &Al[(4096 + wave * 1024) >> 1];
    ushort_t* ldsB0 = &Bl[(wave * 1024) >> 1];
    ushort_t* ldsB1 = &Bl[(4096 + wave * 1024) >> 1];

    f32x4 acc[4][4];
    #pragma unroll
    for (int i = 0; i < 4; ++i)
        #pragma unroll
        for (int j = 0; j < 4; ++j) acc[i][j] = f32x4{0.f, 0.f, 0.f, 0.f};

    const ushort_t* Ap = A + (size_t)row0 * K;
    const ushort_t* Bp = Bt + (size_t)col0 * K;

    for (int k0 = 0; k0 < K; k0 += 32) {
        __syncthreads();
        gload_lds16(Ap + (size_t)r0 * K + k0 + c0, ldsA0);
        gload_lds16(Ap + (size_t)r1 * K + k0 + c1, ldsA1);
        gload_lds16(Bp + (size_t)r0 * K + k0 + c0, ldsB0);
        gload_lds16(Bp + (size_t)r1 * K + k0 + c1, ldsB1);
        __syncthreads();
        short8 af[4], bfr[4];
        #pragma unroll
        for (int f = 0; f < 4; ++f)
            af[f] = *(const short8*)(&Al[(wr * 64 + f * 16 + lm) * 32 + lk]);
        #pragma unroll
        for (int f = 0; f < 4; ++f)
            bfr[f] = *(const short8*)(&Bl[(wc * 64 + f * 16 + lm) * 32 + lk]);
        #pragma unroll
        for (int i = 0; i < 4; ++i)
            #pragma unroll
            for (int j = 0; j < 4; ++j)
                acc[i][j] = __builtin_amdgcn_mfma_f32_16x16x32_bf16(af[i], bfr[j], acc[i][j], 0, 0, 0);
    }
    const int orow = row0 + wr * 64 + (lane >> 4) * 4;
    const int ocol = col0 + wc * 64 + lm;
    #pragma unroll
    for (int i = 0; i < 4; ++i)
        #pragma unroll
        for (int j = 0; j < 4; ++j)
            #pragma unroll
            for (int e = 0; e < 4; ++e) {
                int rr = orow + i * 16 + e, cc = ocol + j * 16;
                if (OUTBF) ((ushort_t*)Cout)[(size_t)rr * N + cc] = f2b(acc[i][j][e]);
                else       ((float*)Cout)[(size_t)rr * N + cc]   = acc[i][j][e];
            }
}

// ---------------------------------------------------------------------------
// lowrank (MFMA): tmp[8192][16] = xbf @ w1t^T.  128 blocks, 64 rows each.
// ---------------------------------------------------------------------------
__global__ __launch_bounds__(256)
void lowrank_mfma(const ushort_t* __restrict__ xbf, const ushort_t* __restrict__ w1t,
                  float* __restrict__ tmp) {
    const int t = threadIdx.x;
    const int w = t >> 6, lane = t & 63;
    const int lm = lane & 15, lg = lane >> 4;
    const int row0 = blockIdx.x * 64 + w * 16;
    f32x4 acc = {0.f, 0.f, 0.f, 0.f};
    #pragma unroll
    for (int kk = 0; kk < 32; ++kk) {
        short8 a = *(const short8*)&xbf[(size_t)(row0 + lm) * DM + kk * 32 + lg * 8];
        short8 b = *(const short8*)&w1t[(size_t)lm * DM + kk * 32 + lg * 8];
        acc = __builtin_amdgcn_mfma_f32_16x16x32_bf16(a, b, acc, 0, 0, 0);
    }
    #pragma unroll
    for (int e = 0; e < 4; ++e)
        tmp[(size_t)(row0 + lg * 4 + e) * 16 + lm] = acc[e];
}

// ---------------------------------------------------------------------------
// gatek: gk[BT,512] = log_sigmoid(tmp @ Wgk2 + b) / 16
// ---------------------------------------------------------------------------
__global__ __launch_bounds__(256)
void gatek_kernel(const float* __restrict__ tmp, const float* __restrict__ W2,
                  const float* __restrict__ bias, float* __restrict__ gk) {
    const int idx = blockIdx.x * 256 + threadIdx.x;
    const int bt = idx >> 9, c = idx & 511;
    float z = bias[c];
    #pragma unroll
    for (int j = 0; j < 16; ++j)
        z += tmp[bt * 16 + j] * W2[j * KD + c];
    float ls = fminf(z, 0.f) - log1pf(expf(-fabsf(z)));
    gk[idx] = ls * GNORM_INV;
}

// ---------------------------------------------------------------------------
// gateprep: q,k,gk (f32) -> qgb,kib,kgb (bf16 per-chunk [64][128]) + glast
// ---------------------------------------------------------------------------
__global__ __launch_bounds__(128)
void gateprep_kernel(const float* __restrict__ q, const float* __restrict__ kf,
                     const float* __restrict__ gk,
                     ushort_t* __restrict__ qgb, ushort_t* __restrict__ kib,
                     ushort_t* __restrict__ kgb, float* __restrict__ glast) {
    const int bid = blockIdx.x;
    const int c = bid & 31, bh = bid >> 5;
    const int b = bh >> 2, h = bh & 3;
    const int d = threadIdx.x;
    const int t0 = b * T_ + c * CC;
    const int gbase = t0 * KD + h * DK_ + d;
    const int obase = bid * (CC * DK_) + d;

    float total = 0.f;
    #pragma unroll 8
    for (int i = 0; i < CC; ++i) total += gk[gbase + i * KD];

    float G = 0.f;
    #pragma unroll 4
    for (int i = 0; i < CC; ++i) {
        const int gi = gbase + i * KD;
        G += gk[gi];
        float qv = q[gi], kv = kf[gi];
        qgb[obase + i * DK_] = f2b(qv * expf(G) * SCALE);
        kib[obase + i * DK_] = f2b(kv * expf(-G));
        kgb[obase + i * DK_] = f2b(kv * expf(total - G));
    }
    glast[bid * DK_ + d] = expf(total);
}

// ---------------------------------------------------------------------------
// vtrans: vbf [bt][VD] -> vT per-chunk [dv=256][j=64]
// ---------------------------------------------------------------------------
__global__ __launch_bounds__(256)
void vtrans_kernel(const ushort_t* __restrict__ vbf, ushort_t* __restrict__ vT) {
    __shared__ ushort_t vl[64][264];
    const int bid = blockIdx.x;
    const int c = bid & 31, bh = bid >> 5;
    const int b = bh >> 2, h = bh & 3;
    const int t0 = b * T_ + c * CC;
    const int t = threadIdx.x;

    #pragma unroll
    for (int m = 0; m < 8; ++m) {
        int p = t + m * 256;
        int j = p >> 5, d8 = (p & 31) * 8;
        *(uint4*)&vl[j][d8] = *(const uint4*)&vbf[(size_t)(t0 + j) * VD + h * DV_ + d8];
    }
    __syncthreads();

    const size_t outb = (size_t)bid * (256 * 64);
    #pragma unroll
    for (int it = 0; it < 2; ++it) {
        int dv = it * 128 + (t >> 1);
        int j0 = (t & 1) * 32;
        u32 vv[16];
        #pragma unroll
        for (int wi = 0; wi < 16; ++wi)
            vv[wi] = (u32)vl[j0 + 2 * wi][dv] | ((u32)vl[j0 + 2 * wi + 1][dv] << 16);
        ushort_t* dst = &vT[outb + (size_t)dv * 64 + j0];
        *(uint4*)(dst + 0)  = make_uint4(vv[0], vv[1], vv[2], vv[3]);
        *(uint4*)(dst + 8)  = make_uint4(vv[4], vv[5], vv[6], vv[7]);
        *(uint4*)(dst + 16) = make_uint4(vv[8], vv[9], vv[10], vv[11]);
        *(uint4*)(dst + 24) = make_uint4(vv[12], vv[13], vv[14], vv[15]);
    }
}

// ---------------------------------------------------------------------------
// chunk_state (MFMA): Sst^T[dv=256][dk=128] = vT(256x64) @ kg(64x128)
// ---------------------------------------------------------------------------
__global__ __launch_bounds__(256)
void chunk_state(const ushort_t* __restrict__ kgb, const ushort_t* __restrict__ vT,
                 ushort_t* __restrict__ Sst) {
    __shared__ ushort_t kgT[128 * 72];
    const int bid = blockIdx.x;
    const int t = threadIdx.x;
    const size_t kgbase = (size_t)bid * (CC * DK_);
    const size_t vtbase = (size_t)bid * (256 * 64);
    const size_t sbase  = (size_t)bid * (256 * 128);

    #pragma unroll
    for (int m = 0; m < 4; ++m) {
        int p = t + m * 256;
        int j = p >> 4, d0 = (p & 15) * 8;
        uint4 r = *(const uint4*)&kgb[kgbase + (size_t)j * DK_ + d0];
        kgT[(d0 + 0) * 72 + j] = (ushort_t)(r.x & 0xffff);
        kgT[(d0 + 1) * 72 + j] = (ushort_t)(r.x >> 16);
        kgT[(d0 + 2) * 72 + j] = (ushort_t)(r.y & 0xffff);
        kgT[(d0 + 3) * 72 + j] = (ushort_t)(r.y >> 16);
        kgT[(d0 + 4) * 72 + j] = (ushort_t)(r.z & 0xffff);
        kgT[(d0 + 5) * 72 + j] = (ushort_t)(r.z >> 16);
        kgT[(d0 + 6) * 72 + j] = (ushort_t)(r.w & 0xffff);
        kgT[(d0 + 7) * 72 + j] = (ushort_t)(r.w >> 16);
    }
    __syncthreads();

    const int w = t >> 6, lane = t & 63;
    const int lm = lane & 15, lg = lane >> 4;
    #pragma unroll
    for (int mm = 0; mm < 4; ++mm) {
        const int mt = w * 4 + mm;
        short8 a0 = *(const short8*)&vT[vtbase + (size_t)(mt * 16 + lm) * 64 + lg * 8];
        short8 a1 = *(const short8*)&vT[vtbase + (size_t)(mt * 16 + lm) * 64 + 32 + lg * 8];
        #pragma unroll
        for (int n = 0; n < 8; ++n) {
            f32x4 acc = {0.f, 0.f, 0.f, 0.f};
            short8 b0 = *(const short8*)&kgT[(n * 16 + lm) * 72 + lg * 8];
            short8 b1 = *(const short8*)&kgT[(n * 16 + lm) * 72 + 32 + lg * 8];
            acc = __builtin_amdgcn_mfma_f32_16x16x32_bf16(a0, b0, acc, 0, 0, 0);
            acc = __builtin_amdgcn_mfma_f32_16x16x32_bf16(a1, b1, acc, 0, 0, 0);
            #pragma unroll
            for (int e = 0; e < 4; ++e)
                Sst[sbase + (size_t)(mt * 16 + lg * 4 + e) * 128 + n * 16 + lm] = f2b(acc[e]);
        }
    }
}

// ---------------------------------------------------------------------------
// scan_combine: in-place M_c -> exclusive prefix P_c. 256 blocks.
// ---------------------------------------------------------------------------
__global__ __launch_bounds__(256)
void scan_combine(ushort_t* __restrict__ Sst, const float* __restrict__ glast) {
    const int bid = blockIdx.x;
    const int dvt = bid & 15, bh = bid >> 4;
    const int t = threadIdx.x;
    const int dv = dvt * 16 + (t >> 4);
    const int dk0 = (t & 15) * 8;

    float P[8];
    #pragma unroll
    for (int e = 0; e < 8; ++e) P[e] = 0.f;

    for (int c = 0; c < NCH; ++c) {
        const size_t base = ((size_t)(bh * NCH + c) * 256 + dv) * 128 + dk0;
        uint4 m0 = *(const uint4*)&Sst[base];
        u32 wd[4];
        #pragma unroll
        for (int e = 0; e < 4; ++e)
            wd[e] = (u32)f2b(P[2 * e]) | ((u32)f2b(P[2 * e + 1]) << 16);
        *(uint4*)&Sst[base] = make_uint4(wd[0], wd[1], wd[2], wd[3]);
        float mv[8];
        unpack2(m0.x, mv[0], mv[1]); unpack2(m0.y, mv[2], mv[3]);
        unpack2(m0.z, mv[4], mv[5]); unpack2(m0.w, mv[6], mv[7]);
        const float* glp = &glast[(size_t)(bh * NCH + c) * DK_ + dk0];
        float4 g0 = *(const float4*)&glp[0];
        float4 g1 = *(const float4*)&glp[4];
        float gl[8] = {g0.x, g0.y, g0.z, g0.w, g1.x, g1.y, g1.z, g1.w};
        #pragma unroll
        for (int e = 0; e < 8; ++e) P[e] = gl[e] * P[e] + mv[e];
    }
}

// ---------------------------------------------------------------------------
// fused_chunk (MFMA): o = tril(qg@ki^T)@v + qg@P per chunk; bf16 out.
// ---------------------------------------------------------------------------
__global__ __launch_bounds__(256)
void fused_chunk(const ushort_t* __restrict__ qgb, const ushort_t* __restrict__ kib,
                 const ushort_t* __restrict__ vT, const ushort_t* __restrict__ Sst,
                 ushort_t* __restrict__ ob) {
    __shared__ __align__(16) ushort_t lds[24064];   // 48.1KB
    ushort_t* stg = lds;                 // [64][168]
    ushort_t* vq  = lds + 10752;         // [64][104]
    ushort_t* Al  = lds + 17408;         // [64][104]

    const int bid = blockIdx.x;
    const int c = bid & 31, bh = bid >> 5;
    const int b = bh >> 2, h = bh & 3;
    const int t0 = b * T_ + c * CC;
    const int t = threadIdx.x;
    const int w = t >> 6, lane = t & 63;
    const int lm = lane & 15, lg = lane >> 4;
    const int m0 = w * 16;

    const size_t qbase  = (size_t)bid * (CC * DK_);
    const size_t vtbase = (size_t)bid * (256 * 64);
    const size_t sbase  = (size_t)bid * (256 * 128);

    short8 qf[4];
    #pragma unroll
    for (int kk = 0; kk < 4; ++kk)
        qf[kk] = *(const short8*)&qgb[qbase + (size_t)(m0 + lm) * DK_ + kk * 32 + lg * 8];

    #pragma unroll
    for (int m = 0; m < 4; ++m) {
        int p = t + m * 256;
        int j = p >> 4, d0 = (p & 15) * 8;
        *(uint4*)&stg[j * 168 + d0] = *(const uint4*)&kib[qbase + (size_t)j * DK_ + d0];
    }
    __syncthreads();

    f32x4 accA[4];
    #pragma unroll
    for (int jt = 0; jt < 4; ++jt) accA[jt] = f32x4{0.f, 0.f, 0.f, 0.f};
    #pragma unroll
    for (int jt = 0; jt < 4; ++jt)
        #pragma unroll
        for (int kk = 0; kk < 4; ++kk) {
            short8 bfrag = *(const short8*)&stg[(jt * 16 + lm) * 168 + kk * 32 + lg * 8];
            accA[jt] = __builtin_amdgcn_mfma_f32_16x16x32_bf16(qf[kk], bfrag, accA[jt], 0, 0, 0);
        }
    #pragma unroll
    for (int jt = 0; jt < 4; ++jt)
        #pragma unroll
        for (int e = 0; e < 4; ++e) {
            int i = m0 + lg * 4 + e, j = jt * 16 + lm;
            Al[i * 104 + j] = f2b(j <= i ? accA[jt][e] : 0.f);
        }
    __syncthreads();

    short8 af[2];
    #pragma unroll
    for (int kk = 0; kk < 2; ++kk)
        af[kk] = *(const short8*)&Al[(m0 + lm) * 104 + kk * 32 + lg * 8];

    #pragma unroll 1
    for (int qq = 0; qq < 4; ++qq) {
        #pragma unroll
        for (int m = 0; m < 2; ++m) {
            int p = t + m * 256;
            int dvr = p >> 3, d0 = (p & 7) * 8;
            *(uint4*)&vq[dvr * 104 + d0] =
                *(const uint4*)&vT[vtbase + (size_t)(qq * 64 + dvr) * 64 + d0];
        }
        #pragma unroll
        for (int m = 0; m < 4; ++m) {
            int p = t + m * 256;
            int dvr = p >> 4, d0 = (p & 15) * 8;
            *(uint4*)&stg[dvr * 168 + d0] =
                *(const uint4*)&Sst[sbase + (size_t)(qq * 64 + dvr) * 128 + d0];
        }
        __syncthreads();
        #pragma unroll
        for (int n = 0; n < 4; ++n) {
            f32x4 acc = {0.f, 0.f, 0.f, 0.f};
            #pragma unroll
            for (int kk = 0; kk < 2; ++kk) {
                short8 bfrag = *(const short8*)&vq[(n * 16 + lm) * 104 + kk * 32 + lg * 8];
                acc = __builtin_amdgcn_mfma_f32_16x16x32_bf16(af[kk], bfrag, acc, 0, 0, 0);
            }
            #pragma unroll
            for (int kk = 0; kk < 4; ++kk) {
                short8 bfrag = *(const short8*)&stg[(n * 16 + lm) * 168 + kk * 32 + lg * 8];
                acc = __builtin_amdgcn_mfma_f32_16x16x32_bf16(qf[kk], bfrag, acc, 0, 0, 0);
            }
            #pragma unroll
            for (int e = 0; e < 4; ++e)
                ob[(size_t)(t0 + m0 + lg * 4 + e) * VD + h * DV_ + qq * 64 + n * 16 + lm] = f2b(acc[e]);
        }
        __syncthreads();
    }
}

// ---------------------------------------------------------------------------
// normgate: obf = bf16( RMSNorm(o)*gnw * swish(g) )
// ---------------------------------------------------------------------------
__global__ __launch_bounds__(256)
void normgate_kernel(const ushort_t* __restrict__ ob, const ushort_t* __restrict__ gbf,
                     const float* __restrict__ gnw, ushort_t* __restrict__ obf) {
    const int t = threadIdx.x;
    const int w = t >> 6, lane = t & 63;
    const int row = blockIdx.x * 4 + w;
    const size_t base = (size_t)row * DV_ + lane * 4;

    uint2 ov2 = *(const uint2*)&ob[base];
    float o0v, o1v, o2v, o3v;
    unpack2(ov2.x, o0v, o1v); unpack2(ov2.y, o2v, o3v);
    float ssq = o0v * o0v + o1v * o1v + o2v * o2v + o3v * o3v;
    #pragma unroll
    for (int off = 32; off > 0; off >>= 1) ssq += __shfl_xor(ssq, off);
    const float rms = rsqrtf(ssq * (1.0f / DV_) + 1e-5f);

    uint2 gv2 = *(const uint2*)&gbf[base];
    float g0, g1, g2, g3;
    unpack2(gv2.x, g0, g1); unpack2(gv2.y, g2, g3);
    float4 wv = *(const float4*)&gnw[lane * 4];
    float r0 = o0v * rms * wv.x * (g0 / (1.f + expf(-g0)));
    float r1 = o1v * rms * wv.y * (g1 / (1.f + expf(-g1)));
    float r2 = o2v * rms * wv.z * (g2 / (1.f + expf(-g2)));
    float r3 = o3v * rms * wv.w * (g3 / (1.f + expf(-g3)));
    uint2 p;
    p.x = (u32)f2b(r0) | ((u32)f2b(r1) << 16);
    p.y = (u32)f2b(r2) | ((u32)f2b(r3) << 16);
    *(uint2*)&obf[base] = p;
}

// ---------------------------------------------------------------------------
extern "C" void kernel_launch(void* const* d_in, const int* in_sizes, int n_in,
                              void* d_out, int out_size, void* d_ws, size_t ws_size,
                              hipStream_t stream) {
    const float* x    = (const float*)d_in[0];
    const float* Wq   = (const float*)d_in[1];
    const float* Wk   = (const float*)d_in[2];
    const float* Wv   = (const float*)d_in[3];
    const float* Wg   = (const float*)d_in[4];
    const float* Wgk1 = (const float*)d_in[5];
    const float* Wgk2 = (const float*)d_in[6];
    const float* bgk2 = (const float*)d_in[7];
    const float* Wo   = (const float*)d_in[8];
    const float* gnw  = (const float*)d_in[9];

    float* ws = (float*)d_ws;
    // ---- workspace plan (f32 word offsets; sizes DERIVED, all audited) ----
    // q     [0,        4194304)  f32 BT*KD (4,194,304 w) ; late: ob bf16 BT*VD (4,194,304 w)
    // kf    [4194304,  8388608)  f32 BT*KD ; late: gbf bf16 BT*VD (exact fit)
    // gk    [8388608, 12582912)  f32 BT*KD
    // vT    [12582912,16777216)  u16 BT*VD (4,194,304 w)
    // Sst   [16777216,25165824)  u16 512*256*128 (8,388,608 w)
    //   early: vbf  [16777216,20971520) u16 BT*VD
    //          wcat [20971520,22020096) u16 2048*1024 (1,048,576 w)
    //          wgt  [22020096,22544384) u16 1024*1024 (524,288 w)
    //   late:  obf  [16777216,20971520), wbfO [20971520,21495808)
    // xbf   [25165824,29360128)  u16 BT*DM (4,194,304 w)
    // qgb   [29360128,31457280)  u16 BT*KD (2,097,152 w)
    // kib   [31457280,33554432)  u16 BT*KD (2,097,152 w)
    // kgb   [33554432,35651584)  u16 BT*KD (2,097,152 w)
    // tmp16 [35651584,35782656)  f32 BT*16 (131,072 w)
    // glast [35782656,35848192)  f32 65,536 w
    // w1t   [35848192,35856384)  u16 16,384 (8,192 w)
    // total 35,856,384 w = 143.4 MB (same as R4's proven footprint)
    float* q       = ws;
    float* kf      = ws + 4194304;
    float* gk      = ws + 8388608;
    ushort_t* vT   = (ushort_t*)(ws + 12582912);
    ushort_t* Sst  = (ushort_t*)(ws + 16777216);
    ushort_t* vbf  = (ushort_t*)(ws + 16777216);
    ushort_t* wcat = (ushort_t*)(ws + 20971520);
    ushort_t* wgt  = (ushort_t*)(ws + 22020096);
    ushort_t* obf  = (ushort_t*)(ws + 16777216);
    ushort_t* wbfO = (ushort_t*)(ws + 20971520);
    ushort_t* ob   = (ushort_t*)ws;
    ushort_t* gbf  = (ushort_t*)(ws + 4194304);
    ushort_t* xbf  = (ushort_t*)(ws + 25165824);
    ushort_t* qgb  = (ushort_t*)(ws + 29360128);
    ushort_t* kib  = (ushort_t*)(ws + 31457280);
    ushort_t* kgb  = (ushort_t*)(ws + 33554432);
    float* tmp16   = ws + 35651584;
    float* glast   = ws + 35782656;
    ushort_t* w1t  = (ushort_t*)(ws + 35848192);

    cvtx<<<4096, 256, 0, stream>>>(x, xbf, BT * DM);
    w1trans<<<64, 256, 0, stream>>>(Wgk1, w1t);

    // concatenated W^T: [q|k|v] rows (2048 x 1024), g weight separate
    tcvt<<<dim3(32, 16), 256, 0, stream>>>(Wq, wcat, DM, KD);
    tcvt<<<dim3(32, 16), 256, 0, stream>>>(Wk, wcat + (size_t)512 * 1024, DM, KD);
    tcvt<<<dim3(32, 32), 256, 0, stream>>>(Wv, wcat + (size_t)1024 * 1024, DM, VD);
    tcvt<<<dim3(32, 32), 256, 0, stream>>>(Wg, wgt, DM, VD);

    gemm_qkv<<<1024, 256, 0, stream>>>(xbf, wcat, q, kf, vbf);

    lowrank_mfma<<<128, 256, 0, stream>>>(xbf, w1t, tmp16);
    gatek_kernel<<<16384, 256, 0, stream>>>(tmp16, Wgk2, bgk2, gk);
    gateprep_kernel<<<512, 128, 0, stream>>>(q, kf, gk, qgb, kib, kgb, glast);

    // g projection into freed kf region (bf16 out); reads xbf + wgt (both alive)
    gemm_bf16<1><<<512, 256, 0, stream>>>(xbf, wgt, gbf, BT, VD, DM, 64);

    vtrans_kernel<<<512, 256, 0, stream>>>(vbf, vT);
    chunk_state<<<512, 256, 0, stream>>>(kgb, vT, Sst);
    scan_combine<<<256, 256, 0, stream>>>(Sst, glast);
    fused_chunk<<<512, 256, 0, stream>>>(qgb, kib, vT, Sst, ob);

    tcvt<<<dim3(32, 32), 256, 0, stream>>>(Wo, wbfO, VD, DM);
    normgate_kernel<<<8192, 256, 0, stream>>>(ob, gbf, gnw, obf);
    gemm_bf16<0><<<512, 256, 0, stream>>>(obf, wbfO, (float*)d_out, BT, DM, VD, 64);
}